// Round 16
// baseline (201.044 us; speedup 1.0000x reference)
//
#include <hip/hip_runtime.h>
#include <hip/hip_bf16.h>
#include <math.h>

#define N 4096
#define G 2048
#define H1 512
#define H2 128
#define HEADS 8
#define EMB 16
#define C 20
#define S 4
#define CH 64
#define CIN_D (H2 + EMB)   // 144
#define KD_PAD 160         // CIN_D padded to multiple of 32
#define KB_PAD 32          // C padded to 32
#define CAP 128
#define EPSV 1e-6f

typedef __attribute__((ext_vector_type(8))) short short8;
typedef __attribute__((ext_vector_type(8))) short bf16x8;
typedef __attribute__((ext_vector_type(4))) float f32x4;

__device__ __forceinline__ unsigned short f2b(float x) {
    __hip_bfloat16 h = __float2bfloat16(x);
    return *reinterpret_cast<unsigned short*>(&h);
}
__device__ __forceinline__ float b2f(unsigned short u) {
    unsigned int x = ((unsigned int)u) << 16;
    return __uint_as_float(x);
}
// Stirling lgamma: ~1e-7 rel for x>=8 (shift loop for smaller x; untaken here
// since th = exp(5) ~ 148).
__device__ __forceinline__ float lgamma_fast(float x) {
    float sh = 0.f;
    while (x < 8.f) { sh -= __logf(x); x += 1.f; }
    float ix = 1.f / x;
    float lx = __logf(x);
    return (x - 0.5f) * lx - x + 0.91893853f
         + ix * (0.08333333f - 0.00277778f * ix * ix) + sh;
}

// ---------------- merged CSR build + prep (tables + bf16 conversions) ----------------
#define SEG_SG   (S * G)
#define SEG_NF4  (N * G / 4)
#define SEG_WE4  (H1 * G / 4)
#define SEG_W24  (H2 * H1 / 4)
#define SEG_WD1E (H1 * KD_PAD)
#define SEG_WD24 (G * H1 / 4)
#define SEG_BTE  (G * KB_PAD)
#define PREP_TOTAL (SEG_SG + SEG_NF4 + SEG_WE4 + SEG_W24 + SEG_WD1E + SEG_WD24 + SEG_BTE)
#define CSR_BLOCKS (N / 4)
#define PREP_BLOCKS ((PREP_TOTAL + 255) / 256)

__device__ __forceinline__ void cvt4(const float* __restrict__ in,
                                     unsigned short* __restrict__ out, int i) {
    float4 v = ((const float4*)in)[i];
    ushort4 o;
    o.x = f2b(v.x); o.y = f2b(v.y); o.z = f2b(v.z); o.w = f2b(v.w);
    ((ushort4*)out)[i] = o;
}

__global__ __launch_bounds__(256) void csr_prep(const float* __restrict__ adj,
                                                int* __restrict__ col_idx,
                                                int* __restrict__ row_cnt,
                                                const float* __restrict__ logtheta,
                                                const float* __restrict__ gamma,
                                                float* __restrict__ th_a, float* __restrict__ eg_a,
                                                float* __restrict__ gm_a, float* __restrict__ ax_a,
                                                const float* __restrict__ node_f,
                                                unsigned short* __restrict__ nf_bf,
                                                const float* __restrict__ We1,
                                                unsigned short* __restrict__ We1_bf,
                                                const float* __restrict__ W2,
                                                unsigned short* __restrict__ W2_bf,
                                                const float* __restrict__ Wd1,
                                                unsigned short* __restrict__ Wd1_bf,
                                                const float* __restrict__ Wd2,
                                                unsigned short* __restrict__ Wd2_bf,
                                                const float* __restrict__ basis,
                                                unsigned short* __restrict__ basisT_bf) {
    int b = blockIdx.x;
    if (b < CSR_BLOCKS) {
        // bitmask CSR: lane owns 64 contiguous columns -> no serial ballot chain
        int wv = threadIdx.x >> 6, lane = threadIdx.x & 63;
        int i = b * 4 + wv;
        const float4* row4 = (const float4*)(adj + (size_t)i * N);
        unsigned long long mask = 0ull;
        #pragma unroll
        for (int q = 0; q < 16; ++q) {
            float4 v = row4[lane * 16 + q];
            if (v.x != 0.f) mask |= 1ull << (q * 4 + 0);
            if (v.y != 0.f) mask |= 1ull << (q * 4 + 1);
            if (v.z != 0.f) mask |= 1ull << (q * 4 + 2);
            if (v.w != 0.f) mask |= 1ull << (q * 4 + 3);
        }
        int cnt = __popcll(mask);
        int incl = cnt;
        #pragma unroll
        for (int off = 1; off < 64; off <<= 1) {
            int v = __shfl_up(incl, off);
            if (lane >= off) incl += v;
        }
        int ofs = incl - cnt;                 // exclusive prefix
        int total = __shfl(incl, 63);
        int* cols = col_idx + (size_t)i * CAP;
        unsigned long long mm = mask;
        while (mm) {
            int j = __ffsll(mm) - 1;
            if (ofs < CAP) cols[ofs] = lane * 64 + j;
            ++ofs;
            mm &= mm - 1;
        }
        if (lane == 0) row_cnt[i] = total < CAP ? total : CAP;
        return;
    }
    int idx = (b - CSR_BLOCKS) * 256 + threadIdx.x;
    if (idx < SEG_SG) {
        float th = __expf(logtheta[idx]);
        float gm = gamma[idx];
        th_a[idx] = th;
        eg_a[idx] = __expf(gm);
        gm_a[idx] = gm;
        ax_a[idx] = th * __logf(th + EPSV) - lgammaf(th + EPSV);
        return;
    }
    idx -= SEG_SG;
    if (idx < SEG_NF4) { cvt4(node_f, nf_bf, idx); return; }
    idx -= SEG_NF4;
    if (idx < SEG_WE4) { cvt4(We1, We1_bf, idx); return; }
    idx -= SEG_WE4;
    if (idx < SEG_W24) { cvt4(W2, W2_bf, idx); return; }
    idx -= SEG_W24;
    if (idx < SEG_WD1E) {
        int n = idx / KD_PAD, k = idx - n * KD_PAD;
        Wd1_bf[idx] = f2b(k < CIN_D ? Wd1[n * CIN_D + k] : 0.f);
        return;
    }
    idx -= SEG_WD1E;
    if (idx < SEG_WD24) { cvt4(Wd2, Wd2_bf, idx); return; }
    idx -= SEG_WD24;
    if (idx < SEG_BTE) {
        int g = idx >> 5, c = idx & 31;
        basisT_bf[idx] = f2b(c < C ? basis[c * G + g] : 0.f);
    }
}

// ---------------- bf16 MFMA GEMM, optional split-K, optional hv epilogue ----------------
#define LDP 40
template<int FM, int OBF, int KS, int HV>
__global__ __launch_bounds__(256) void gemm_mfma(const unsigned short* __restrict__ A,
                                                 const unsigned short* __restrict__ B,
                                                 const float* __restrict__ bias,
                                                 void* __restrict__ Cout,
                                                 int M, int Nc, int K,
                                                 const float* __restrict__ v0f,
                                                 const float* __restrict__ v1f,
                                                 float* __restrict__ hv0,
                                                 float* __restrict__ hv1) {
    constexpr int BMT = FM * 32;
    __shared__ short As[BMT * LDP];
    __shared__ short Bs[128 * LDP];
    int bn = blockIdx.x, bm = blockIdx.y;
    int kz = (KS > 1) ? blockIdx.z : 0;
    int t = threadIdx.x;
    int lane = t & 63, wid = t >> 6;
    int wr = wid >> 1, wc = wid & 1;
    f32x4 acc[FM][4] = {};
    const short* Ag = (const short*)A + (size_t)(bm * BMT) * K;
    const short* Bg = (const short*)B + (size_t)(bn * 128) * K;
    int r0 = t >> 2, q0 = t & 3;
    int rbase = (lane & 15);
    int koff = (lane >> 4) * 8;
    int kbeg = kz * (K / KS), kend = kbeg + K / KS;

    for (int k0 = kbeg; k0 < kend; k0 += 32) {
        short8 a0 = *(const short8*)(Ag + (size_t)r0 * K + k0 + q0 * 8);
        short8 a1;
        if constexpr (FM == 4) a1 = *(const short8*)(Ag + (size_t)(r0 + 64) * K + k0 + q0 * 8);
        short8 b0 = *(const short8*)(Bg + (size_t)r0 * K + k0 + q0 * 8);
        short8 b1 = *(const short8*)(Bg + (size_t)(r0 + 64) * K + k0 + q0 * 8);
        __syncthreads();
        *(short8*)(As + r0 * LDP + q0 * 8) = a0;
        if constexpr (FM == 4) *(short8*)(As + (r0 + 64) * LDP + q0 * 8) = a1;
        *(short8*)(Bs + r0 * LDP + q0 * 8) = b0;
        *(short8*)(Bs + (r0 + 64) * LDP + q0 * 8) = b1;
        __syncthreads();
        bf16x8 af[FM], bfr[4];
        #pragma unroll
        for (int m = 0; m < FM; ++m)
            af[m] = *(const bf16x8*)(As + (wr * FM * 16 + m * 16 + rbase) * LDP + koff);
        #pragma unroll
        for (int n = 0; n < 4; ++n)
            bfr[n] = *(const bf16x8*)(Bs + (wc * 64 + n * 16 + rbase) * LDP + koff);
        #pragma unroll
        for (int m = 0; m < FM; ++m)
            #pragma unroll
            for (int n = 0; n < 4; ++n)
                acc[m][n] = __builtin_amdgcn_mfma_f32_16x16x32_bf16(af[m], bfr[n], acc[m][n], 0, 0, 0);
    }
    int colb = bn * 128 + wc * 64;
    int rowb = bm * BMT + wr * FM * 16;
    #pragma unroll
    for (int m = 0; m < FM; ++m) {
        #pragma unroll
        for (int n = 0; n < 4; ++n) {
            int col = colb + n * 16 + (lane & 15);
            int row0 = rowb + m * 16 + (lane >> 4) * 4;
            if constexpr (KS > 1) {
                float* Cp = (float*)Cout + (size_t)kz * M * Nc;
                #pragma unroll
                for (int r = 0; r < 4; ++r)
                    Cp[(size_t)(row0 + r) * Nc + col] = acc[m][n][r];
            } else {
                float bs = bias ? bias[col] : 0.f;
                #pragma unroll
                for (int r = 0; r < 4; ++r) {
                    float v = acc[m][n][r] + bs;
                    if constexpr (OBF)
                        ((unsigned short*)Cout)[(size_t)(row0 + r) * Nc + col] = f2b(v);
                    else
                        ((float*)Cout)[(size_t)(row0 + r) * Nc + col] = v;
                }
            }
        }
    }
    if constexpr (HV) {
        int h = colb >> 6;
        #pragma unroll
        for (int m = 0; m < FM; ++m) {
            #pragma unroll
            for (int r = 0; r < 4; ++r) {
                int row = rowb + m * 16 + (lane >> 4) * 4 + r;
                float p0 = 0.f, p1 = 0.f;
                #pragma unroll
                for (int n = 0; n < 4; ++n) {
                    int col = colb + n * 16 + (lane & 15);
                    float v = acc[m][n][r] + bias[col];
                    p0 += v * v0f[col];
                    p1 += v * v1f[col];
                }
                p0 += __shfl_xor(p0, 1); p0 += __shfl_xor(p0, 2);
                p0 += __shfl_xor(p0, 4); p0 += __shfl_xor(p0, 8);
                p1 += __shfl_xor(p1, 1); p1 += __shfl_xor(p1, 2);
                p1 += __shfl_xor(p1, 4); p1 += __shfl_xor(p1, 8);
                if ((lane & 15) == 0) {
                    hv0[row * HEADS + h] = p0;
                    hv1[row * HEADS + h] = p1;
                }
            }
        }
    }
}

// ---------------- shared FM=2, bf16-out GEMM body for the merged dec_bd kernel ----------------
template<int HV>
__device__ __forceinline__ void gemm_body2(const unsigned short* __restrict__ A,
                                           const unsigned short* __restrict__ B,
                                           const float* __restrict__ bias,
                                           unsigned short* __restrict__ Cout,
                                           int K, int Nc, int bn, int bm,
                                           const float* __restrict__ v0f,
                                           const float* __restrict__ v1f,
                                           float* __restrict__ hv0,
                                           float* __restrict__ hv1,
                                           short* As, short* Bs) {
    int t = threadIdx.x;
    int lane = t & 63, wid = t >> 6;
    int wr = wid >> 1, wc = wid & 1;
    f32x4 acc[2][4] = {};
    const short* Ag = (const short*)A + (size_t)(bm * 64) * K;
    const short* Bg = (const short*)B + (size_t)(bn * 128) * K;
    int r0 = t >> 2, q0 = t & 3;
    int rbase = (lane & 15);
    int koff = (lane >> 4) * 8;
    for (int k0 = 0; k0 < K; k0 += 32) {
        short8 a0 = *(const short8*)(Ag + (size_t)r0 * K + k0 + q0 * 8);
        short8 b0 = *(const short8*)(Bg + (size_t)r0 * K + k0 + q0 * 8);
        short8 b1 = *(const short8*)(Bg + (size_t)(r0 + 64) * K + k0 + q0 * 8);
        __syncthreads();
        *(short8*)(As + r0 * LDP + q0 * 8) = a0;
        *(short8*)(Bs + r0 * LDP + q0 * 8) = b0;
        *(short8*)(Bs + (r0 + 64) * LDP + q0 * 8) = b1;
        __syncthreads();
        bf16x8 af[2], bfr[4];
        #pragma unroll
        for (int m = 0; m < 2; ++m)
            af[m] = *(const bf16x8*)(As + (wr * 32 + m * 16 + rbase) * LDP + koff);
        #pragma unroll
        for (int n = 0; n < 4; ++n)
            bfr[n] = *(const bf16x8*)(Bs + (wc * 64 + n * 16 + rbase) * LDP + koff);
        #pragma unroll
        for (int m = 0; m < 2; ++m)
            #pragma unroll
            for (int n = 0; n < 4; ++n)
                acc[m][n] = __builtin_amdgcn_mfma_f32_16x16x32_bf16(af[m], bfr[n], acc[m][n], 0, 0, 0);
    }
    int colb = bn * 128 + wc * 64;
    int rowb = bm * 64 + wr * 32;
    #pragma unroll
    for (int m = 0; m < 2; ++m) {
        #pragma unroll
        for (int n = 0; n < 4; ++n) {
            int col = colb + n * 16 + (lane & 15);
            int row0 = rowb + m * 16 + (lane >> 4) * 4;
            float bs = bias ? bias[col] : 0.f;
            #pragma unroll
            for (int r = 0; r < 4; ++r)
                Cout[(size_t)(row0 + r) * Nc + col] = f2b(acc[m][n][r] + bs);
        }
    }
    if constexpr (HV) {
        int h = colb >> 6;
        #pragma unroll
        for (int m = 0; m < 2; ++m) {
            #pragma unroll
            for (int r = 0; r < 4; ++r) {
                int row = rowb + m * 16 + (lane >> 4) * 4 + r;
                float p0 = 0.f, p1 = 0.f;
                #pragma unroll
                for (int n = 0; n < 4; ++n) {
                    int col = colb + n * 16 + (lane & 15);
                    float v = acc[m][n][r] + bias[col];
                    p0 += v * v0f[col];
                    p1 += v * v1f[col];
                }
                p0 += __shfl_xor(p0, 1); p0 += __shfl_xor(p0, 2);
                p0 += __shfl_xor(p0, 4); p0 += __shfl_xor(p0, 8);
                p1 += __shfl_xor(p1, 1); p1 += __shfl_xor(p1, 2);
                p1 += __shfl_xor(p1, 4); p1 += __shfl_xor(p1, 8);
                if ((lane & 15) == 0) {
                    hv0[row * HEADS + h] = p0;
                    hv1[row * HEADS + h] = p1;
                }
            }
        }
    }
}

// merged: blocks [0,256) decoder GEMM (K=160, +hv); blocks [256,1280) BD GEMM (K=32)
__global__ __launch_bounds__(256) void dec_bd(const unsigned short* __restrict__ Xd_bf,
                                              const unsigned short* __restrict__ Wd1_bf,
                                              const float* __restrict__ bd1,
                                              unsigned short* __restrict__ Hlin_bf,
                                              const float* __restrict__ v0d1,
                                              const float* __restrict__ v1d1,
                                              float* __restrict__ hv0,
                                              float* __restrict__ hv1,
                                              const unsigned short* __restrict__ beta_bf,
                                              const unsigned short* __restrict__ basisT_bf,
                                              unsigned short* __restrict__ BDb) {
    __shared__ short As[64 * LDP];
    __shared__ short Bs[128 * LDP];
    int b = blockIdx.x;
    if (b < (H1 / 128) * (N / 64)) {
        gemm_body2<1>(Xd_bf, Wd1_bf, bd1, Hlin_bf, KD_PAD, H1,
                      b % (H1 / 128), b / (H1 / 128), v0d1, v1d1, hv0, hv1, As, Bs);
    } else {
        int b2 = b - (H1 / 128) * (N / 64);
        gemm_body2<0>(beta_bf, basisT_bf, nullptr, BDb, KB_PAD, G,
                      b2 % (G / 128), b2 / (G / 128), nullptr, nullptr, nullptr, nullptr, As, Bs);
    }
}

// ---------------- split-K reduce + bf16 out + fused head dots (Nc=512) ----------------
template<int KS>
__global__ __launch_bounds__(256) void reduce_k_hv(const float* __restrict__ Cp,
                                                   const float* __restrict__ bias,
                                                   unsigned short* __restrict__ out,
                                                   const float* __restrict__ v0f,
                                                   const float* __restrict__ v1f,
                                                   float* __restrict__ hv0,
                                                   float* __restrict__ hv1) {
    constexpr int total4 = N * H1 / 4;
    int t = threadIdx.x;
    int i = blockIdx.x * 256 + t;
    float4 s = ((const float4*)Cp)[i];
    #pragma unroll
    for (int ks = 1; ks < KS; ++ks) {
        float4 v = ((const float4*)(Cp + (size_t)ks * total4 * 4))[i];
        s.x += v.x; s.y += v.y; s.z += v.z; s.w += v.w;
    }
    int col = (i * 4) & (H1 - 1);
    s.x += bias[col]; s.y += bias[col + 1]; s.z += bias[col + 2]; s.w += bias[col + 3];
    ushort4 o;
    o.x = f2b(s.x); o.y = f2b(s.y); o.z = f2b(s.z); o.w = f2b(s.w);
    ((ushort4*)out)[i] = o;
    int row = (i * 4) >> 9;
    int h = col >> 6;
    float4 w0 = *(const float4*)(v0f + col);
    float4 w1 = *(const float4*)(v1f + col);
    float p0 = s.x * w0.x + s.y * w0.y + s.z * w0.z + s.w * w0.w;
    float p1 = s.x * w1.x + s.y * w1.y + s.z * w1.z + s.w * w1.w;
    p0 += __shfl_xor(p0, 1); p0 += __shfl_xor(p0, 2);
    p0 += __shfl_xor(p0, 4); p0 += __shfl_xor(p0, 8);
    p1 += __shfl_xor(p1, 1); p1 += __shfl_xor(p1, 2);
    p1 += __shfl_xor(p1, 4); p1 += __shfl_xor(p1, 8);
    if ((t & 15) == 0) {
        hv0[row * HEADS + h] = p0;
        hv1[row * HEADS + h] = p1;
    }
}

// ---------------- fused Z split-K reduce + per-node (wave = node) ----------------
__global__ __launch_bounds__(256) void z_pernode(const float* __restrict__ Cp,
                                                 const float* __restrict__ b2,
                                                 const float* __restrict__ emb_table,
                                                 const int* __restrict__ slab,
                                                 const float* __restrict__ Wb,
                                                 const float* __restrict__ bb,
                                                 const float* __restrict__ Wa,
                                                 const float* __restrict__ ba,
                                                 const float* __restrict__ lib,
                                                 unsigned short* __restrict__ beta_bf,
                                                 float* __restrict__ muf,
                                                 float* __restrict__ kco,
                                                 unsigned short* __restrict__ Xdb) {
    __shared__ float sZ[4][H2];
    __shared__ float sE[4][EMB];
    __shared__ float sLog[4][C];
    __shared__ float sAl[4];
    int wv = threadIdx.x >> 6;
    int lane = threadIdx.x & 63;
    int i = blockIdx.x * 4 + wv;
    float z0 = 0.f, z1 = 0.f;
    #pragma unroll
    for (int ks = 0; ks < 8; ++ks) {
        const float* P = Cp + (size_t)ks * N * H2 + (size_t)i * H2;
        z0 += P[lane];
        z1 += P[64 + lane];
    }
    z0 += b2[lane];
    z1 += b2[64 + lane];
    sZ[wv][lane] = z0;
    sZ[wv][64 + lane] = z1;
    int s = slab[i];
    if (lane < EMB) sE[wv][lane] = emb_table[s * EMB + lane];
    __syncthreads();
    Xdb[(size_t)i * KD_PAD + lane] = f2b(z0);
    Xdb[(size_t)i * KD_PAD + 64 + lane] = f2b(z1);
    if (lane < EMB) Xdb[(size_t)i * KD_PAD + H2 + lane] = f2b(sE[wv][lane]);
    if (lane < KD_PAD - CIN_D) Xdb[(size_t)i * KD_PAD + CIN_D + lane] = 0;
    if (lane < C) {
        float acc = bb[lane];
        for (int k = 0; k < H2; ++k) {
            float z = sZ[wv][k];
            float e = z > 0.f ? z : expm1f(z);
            acc += e * Wb[lane * H2 + k];
        }
        sLog[wv][lane] = acc;
    }
    __syncthreads();
    if (lane == 0) {
        float mx = sLog[wv][0];
        for (int c = 1; c < C; ++c) mx = fmaxf(mx, sLog[wv][c]);
        float sm = 0.f;
        for (int c = 0; c < C; ++c) { float e = __expf(sLog[wv][c] - mx); sLog[wv][c] = e; sm += e; }
        for (int c = 0; c < C; ++c) sLog[wv][c] /= sm;
    }
    __syncthreads();
    if (lane < KB_PAD) beta_bf[(size_t)i * KB_PAD + lane] = (lane < C) ? f2b(sLog[wv][lane]) : 0;
    float x0 = z0; x0 = x0 > 0.f ? x0 : expm1f(x0);
    float x1 = z1; x1 = x1 > 0.f ? x1 : expm1f(x1);
    float p = x0 * Wa[lane] + x1 * Wa[64 + lane];
    if (lane < EMB) {
        float x2 = sE[wv][lane]; x2 = x2 > 0.f ? x2 : expm1f(x2);
        p += x2 * Wa[H2 + lane];
    }
    #pragma unroll
    for (int m = 32; m; m >>= 1) p += __shfl_xor(p, m);
    if (lane == 0) sAl[wv] = p + ba[0];
    __syncthreads();
    if (lane == 0) {
        float A = sAl[wv], L = lib[i];
        muf[i] = L * __expf(A);
        kco[i] = __logf(L) + A;
    }
}

// ---------------- fused reconstruction GEMM (64x128 tile) + (nf - Xr)^2 ----------------
__global__ __launch_bounds__(256) void gemm_recon_sq(const unsigned short* __restrict__ A,
                                                     const unsigned short* __restrict__ B,
                                                     const float* __restrict__ bias,
                                                     const unsigned short* __restrict__ nfb,
                                                     float* __restrict__ sq_part) {
    constexpr int K = H1;
    __shared__ short As[64 * LDP];
    __shared__ short Bs[128 * LDP];
    __shared__ float red[4][32];
    int bn = blockIdx.x, bm = blockIdx.y;
    int t = threadIdx.x;
    int lane = t & 63, wid = t >> 6;
    int wr = wid >> 1, wc = wid & 1;
    f32x4 acc[2][4] = {};
    const short* Ag = (const short*)A + (size_t)(bm * 64) * K;
    const short* Bg = (const short*)B + (size_t)(bn * 128) * K;
    int r0 = t >> 2, q0 = t & 3;
    int rbase = (lane & 15);
    int koff = (lane >> 4) * 8;

    for (int k0 = 0; k0 < K; k0 += 32) {
        short8 a0 = *(const short8*)(Ag + (size_t)r0 * K + k0 + q0 * 8);
        short8 b0 = *(const short8*)(Bg + (size_t)r0 * K + k0 + q0 * 8);
        short8 b1 = *(const short8*)(Bg + (size_t)(r0 + 64) * K + k0 + q0 * 8);
        __syncthreads();
        *(short8*)(As + r0 * LDP + q0 * 8) = a0;
        *(short8*)(Bs + r0 * LDP + q0 * 8) = b0;
        *(short8*)(Bs + (r0 + 64) * LDP + q0 * 8) = b1;
        __syncthreads();
        bf16x8 af[2], bfr[4];
        #pragma unroll
        for (int m = 0; m < 2; ++m)
            af[m] = *(const bf16x8*)(As + (wr * 32 + m * 16 + rbase) * LDP + koff);
        #pragma unroll
        for (int n = 0; n < 4; ++n)
            bfr[n] = *(const bf16x8*)(Bs + (wc * 64 + n * 16 + rbase) * LDP + koff);
        #pragma unroll
        for (int m = 0; m < 2; ++m)
            #pragma unroll
            for (int n = 0; n < 4; ++n)
                acc[m][n] = __builtin_amdgcn_mfma_f32_16x16x32_bf16(af[m], bfr[n], acc[m][n], 0, 0, 0);
    }
    int colb = bn * 128 + wc * 64;
    int rowb = bm * 64 + wr * 32;
    float part[2][4];
    #pragma unroll
    for (int m = 0; m < 2; ++m) {
        #pragma unroll
        for (int r = 0; r < 4; ++r) part[m][r] = 0.f;
        #pragma unroll
        for (int n = 0; n < 4; ++n) {
            int col = colb + n * 16 + (lane & 15);
            float bs = bias[col];
            int row0 = rowb + m * 16 + (lane >> 4) * 4;
            #pragma unroll
            for (int r = 0; r < 4; ++r) {
                float d = b2f(nfb[(size_t)(row0 + r) * G + col]) - (acc[m][n][r] + bs);
                part[m][r] += d * d;
            }
        }
    }
    #pragma unroll
    for (int m = 0; m < 2; ++m)
        #pragma unroll
        for (int r = 0; r < 4; ++r) {
            float v = part[m][r];
            v += __shfl_xor(v, 1); v += __shfl_xor(v, 2);
            v += __shfl_xor(v, 4); v += __shfl_xor(v, 8);
            part[m][r] = v;
        }
    if ((lane & 15) == 0) {
        int q = lane >> 4;
        #pragma unroll
        for (int m = 0; m < 2; ++m)
            #pragma unroll
            for (int r = 0; r < 4; ++r)
                red[wid][m * 16 + q * 4 + r] = part[m][r];
    }
    __syncthreads();
    if (t < 64) {
        int wr2 = t >> 5, loc = t & 31;
        float v = red[wr2 * 2 + 0][loc] + red[wr2 * 2 + 1][loc];
        sq_part[(size_t)(bm * 64 + t) * 16 + bn] = v;
    }
}

// ---------------- NB log-likelihood row body (wave computes one row) ----------------
__device__ __forceinline__ void nb_row_body(int row, int lane,
                                            const unsigned short* __restrict__ BDb,
                                            const float* __restrict__ cm,
                                            const int* __restrict__ slab,
                                            const float* __restrict__ muf,
                                            const float* __restrict__ kco,
                                            const float* __restrict__ th_a,
                                            const float* __restrict__ eg_a,
                                            const float* __restrict__ gm_a,
                                            const float* __restrict__ ax_a,
                                            float* __restrict__ ll_row) {
    int sl = slab[row];
    float mufv = muf[row], kcov = kco[row];
    const unsigned short* bdr = BDb + (size_t)row * G;
    const float* cmr = cm + (size_t)row * G;
    size_t sgb = (size_t)sl * G;
    float acc = 0.f;
    #pragma unroll 2
    for (int it = 0; it < G / 256; ++it) {
        int c = it * 256 + lane * 4;
        ushort4 bdu = *(const ushort4*)(bdr + c);
        f32x4 k4  = *(const f32x4*)(cmr + c);
        f32x4 th4 = *(const f32x4*)(th_a + sgb + c);
        f32x4 eg4 = *(const f32x4*)(eg_a + sgb + c);
        f32x4 gm4 = *(const f32x4*)(gm_a + sgb + c);
        f32x4 ax4 = *(const f32x4*)(ax_a + sgb + c);
        float bdv[4] = {b2f(bdu.x), b2f(bdu.y), b2f(bdu.z), b2f(bdu.w)};
        #pragma unroll
        for (int j = 0; j < 4; ++j) {
            float th = th4[j], k = k4[j];
            float ebd = bdv[j] + EPSV;
            float lbd = __logf(ebd);
            float mu = mufv * ebd * eg4[j];
            float lgx = lgamma_fast(k + th + EPSV);
            acc += lgx + ax4[j] - (th + k) * __logf(th + mu + EPSV)
                 + k * (kcov + lbd + gm4[j]);
        }
    }
    #pragma unroll
    for (int m = 32; m; m >>= 1) acc += __shfl_xor(acc, m);
    if (lane == 0) ll_row[row] = acc;
}

// ---------------- attention body (weights in LDS + aggregation + elu -> bf16) ----------------
__device__ __forceinline__ void attn_body(int i, int t,
                                          const unsigned short* __restrict__ Hb,
                                          const float* __restrict__ hv0,
                                          const float* __restrict__ hv1,
                                          const int* __restrict__ col_idx,
                                          const int* __restrict__ row_cnt,
                                          unsigned short* __restrict__ outp) {
    __shared__ int scols[CAP];
    __shared__ float sw[CAP][HEADS];
    __shared__ float sden[HEADS];
    __shared__ float red[8][64 * 8];
    int cnt = row_cnt[i];
    const int* cols = col_idx + (size_t)i * CAP;
    if (t < cnt) scols[t] = cols[t];
    __syncthreads();
    for (int idx = t; idx < cnt * HEADS; idx += 512) {
        int e = idx >> 3, h = idx & 7;
        int j = scols[e];
        float x = hv0[i * HEADS + h] + hv1[j * HEADS + h];
        sw[e][h] = __expf(1.f / (1.f + __expf(-x)) - 0.5f);
    }
    __syncthreads();
    if (t < HEADS) {
        float d = 0.f;
        for (int e = 0; e < cnt; ++e) d += sw[e][t];
        sden[t] = 1.f / d;
    }
    __syncthreads();
    int slot = t >> 6;
    int cg = t & 63;
    int h = cg >> 3;
    float inv = sden[h];
    float acc[8];
    #pragma unroll
    for (int k = 0; k < 8; ++k) acc[k] = 0.f;
    for (int e = slot; e < cnt; e += 8) {
        int j = scols[e];
        float wv = sw[e][h] * inv;
        short8 hvv = ((const short8*)(Hb + (size_t)j * H1))[cg];
        #pragma unroll
        for (int k = 0; k < 8; ++k)
            acc[k] += wv * b2f((unsigned short)hvv[k]);
    }
    #pragma unroll
    for (int k = 0; k < 8; ++k) red[slot][cg * 8 + k] = acc[k];
    __syncthreads();
    if (slot < 4) {
        #pragma unroll
        for (int k = 0; k < 8; ++k) red[slot][cg * 8 + k] += red[slot + 4][cg * 8 + k];
    }
    __syncthreads();
    if (slot < 2) {
        #pragma unroll
        for (int k = 0; k < 8; ++k) red[slot][cg * 8 + k] += red[slot + 2][cg * 8 + k];
    }
    __syncthreads();
    if (slot == 0) {
        short8 o;
        #pragma unroll
        for (int k = 0; k < 8; ++k) {
            float v = red[0][cg * 8 + k] + red[1][cg * 8 + k];
            v = (v > 0.f) ? v : expm1f(v);
            o[k] = (short)f2b(v);
        }
        ((short8*)(outp + (size_t)i * H1))[cg] = o;
    }
}

__global__ __launch_bounds__(512) void attn_fused(const unsigned short* __restrict__ Hb,
                                                  const float* __restrict__ hv0,
                                                  const float* __restrict__ hv1,
                                                  const int* __restrict__ col_idx,
                                                  const int* __restrict__ row_cnt,
                                                  unsigned short* __restrict__ out) {
    attn_body(blockIdx.x, threadIdx.x, Hb, hv0, hv1, col_idx, row_cnt, out);
}

// merged: blocks [0,N) decoder attention; blocks [N, N+N/8) NB loss (8 rows/block)
__global__ __launch_bounds__(512) void post_dec(const unsigned short* __restrict__ Hlin_bf,
                                                const float* __restrict__ hv0,
                                                const float* __restrict__ hv1,
                                                const int* __restrict__ col_idx,
                                                const int* __restrict__ row_cnt,
                                                unsigned short* __restrict__ Hgat_bf,
                                                const unsigned short* __restrict__ BDb,
                                                const float* __restrict__ cm,
                                                const int* __restrict__ slab,
                                                const float* __restrict__ muf,
                                                const float* __restrict__ kco,
                                                const float* __restrict__ th_a,
                                                const float* __restrict__ eg_a,
                                                const float* __restrict__ gm_a,
                                                const float* __restrict__ ax_a,
                                                float* __restrict__ ll_row) {
    int b = blockIdx.x;
    if (b < N) {
        attn_body(b, threadIdx.x, Hlin_bf, hv0, hv1, col_idx, row_cnt, Hgat_bf);
    } else {
        int row = (b - N) * 8 + (threadIdx.x >> 6);
        nb_row_body(row, threadIdx.x & 63, BDb, cm, slab, muf, kco,
                    th_a, eg_a, gm_a, ax_a, ll_row);
    }
}

// ---------------- single-block final reduce ----------------
__global__ __launch_bounds__(256) void final_reduce(const float* __restrict__ ll_row,
                                                    const float* __restrict__ sq_part,
                                                    float* __restrict__ out) {
    int t = threadIdx.x;
    float s1 = 0.f, sb = 0.f;
    for (int row = t; row < N; row += 256) {
        s1 += ll_row[row];
        float s2 = 0.f;
        #pragma unroll
        for (int j = 0; j < 16; ++j) s2 += sq_part[(size_t)row * 16 + j];
        sb += sqrtf(s2);
    }
    __shared__ float r1[256], r2[256];
    r1[t] = s1; r2[t] = sb;
    __syncthreads();
    for (int o = 128; o; o >>= 1) {
        if (t < o) { r1[t] += r1[t + o]; r2[t] += r2[t + o]; }
        __syncthreads();
    }
    if (t == 0) out[0] = -(r1[0] / (float)N) + 0.1f * (r2[0] / (float)N);
}

extern "C" void kernel_launch(void* const* d_in, const int* in_sizes, int n_in,
                              void* d_out, int out_size, void* d_ws, size_t ws_size,
                              hipStream_t stream) {
    const float* adj       = (const float*)d_in[0];
    const float* node_f    = (const float*)d_in[1];
    const float* count_m   = (const float*)d_in[2];
    const float* lib       = (const float*)d_in[3];
    const int*   slab      = (const int*)d_in[4];
    const float* basis     = (const float*)d_in[5];
    const float* We1       = (const float*)d_in[6];
    const float* be1       = (const float*)d_in[7];
    const float* v0e1      = (const float*)d_in[8];
    const float* v1e1      = (const float*)d_in[9];
    const float* W2        = (const float*)d_in[10];
    const float* b2        = (const float*)d_in[11];
    const float* Wd1       = (const float*)d_in[12];
    const float* bd1       = (const float*)d_in[13];
    const float* v0d1      = (const float*)d_in[14];
    const float* v1d1      = (const float*)d_in[15];
    const float* Wd2       = (const float*)d_in[16];
    const float* bd2       = (const float*)d_in[17];
    const float* Wa        = (const float*)d_in[18];
    const float* ba        = (const float*)d_in[19];
    const float* Wb        = (const float*)d_in[20];
    const float* bb        = (const float*)d_in[21];
    const float* gamma     = (const float*)d_in[22];
    const float* logtheta  = (const float*)d_in[23];
    const float* emb_table = (const float*)d_in[24];
    float* out = (float*)d_out;

    char* w = (char*)d_ws;
    auto alloc = [&](size_t bytes) { void* p = (void*)w; w += (bytes + 255) & ~(size_t)255; return p; };
    int*   col_idx = (int*)  alloc((size_t)N * CAP * 4);
    int*   row_cnt = (int*)  alloc((size_t)N * 4);
    unsigned short* Hlin_bf = (unsigned short*)alloc((size_t)N * H1 * 2);
    unsigned short* Hgat_bf = (unsigned short*)alloc((size_t)N * H1 * 2);
    unsigned short* Xd_bf   = (unsigned short*)alloc((size_t)N * KD_PAD * 2);
    unsigned short* beta_bf = (unsigned short*)alloc((size_t)N * KB_PAD * 2);
    float* muf     = (float*)alloc((size_t)N * 4);
    float* kco     = (float*)alloc((size_t)N * 4);
    float* hv0     = (float*)alloc((size_t)N * HEADS * 4);
    float* hv1     = (float*)alloc((size_t)N * HEADS * 4);
    float* th_a    = (float*)alloc((size_t)S * G * 4);
    float* eg_a    = (float*)alloc((size_t)S * G * 4);
    float* gm_a    = (float*)alloc((size_t)S * G * 4);
    float* ax_a    = (float*)alloc((size_t)S * G * 4);
    float* Cp      = (float*)alloc((size_t)4 * N * H1 * 4);   // 32 MB split-K partials
    unsigned short* BDb = (unsigned short*)alloc((size_t)N * G * 2);
    float* ll_row  = (float*)alloc((size_t)N * 4);
    float* sq_part = (float*)alloc((size_t)N * 16 * 4);
    unsigned short* nf_bf    = (unsigned short*)alloc((size_t)N * G * 2);
    unsigned short* We1_bf   = (unsigned short*)alloc((size_t)H1 * G * 2);
    unsigned short* W2_bf    = (unsigned short*)alloc((size_t)H2 * H1 * 2);
    unsigned short* Wd1_bf   = (unsigned short*)alloc((size_t)H1 * KD_PAD * 2);
    unsigned short* Wd2_bf   = (unsigned short*)alloc((size_t)G * H1 * 2);
    unsigned short* basisT_bf= (unsigned short*)alloc((size_t)G * KB_PAD * 2);

    // 0. merged CSR + prep
    csr_prep<<<dim3(CSR_BLOCKS + PREP_BLOCKS), dim3(256), 0, stream>>>(
        adj, col_idx, row_cnt, logtheta, gamma, th_a, eg_a, gm_a, ax_a,
        node_f, nf_bf, We1, We1_bf, W2, W2_bf, Wd1, Wd1_bf, Wd2, Wd2_bf, basis, basisT_bf);

    // 1. encoder linear, split-K=4 -> reduce(+head dots) -> bf16 Hlin + hv
    gemm_mfma<2, 0, 4, 0><<<dim3(H1 / 128, N / 64, 4), dim3(256), 0, stream>>>(
        nf_bf, We1_bf, be1, Cp, N, H1, G, nullptr, nullptr, nullptr, nullptr);
    reduce_k_hv<4><<<dim3(N * H1 / 4 / 256), dim3(256), 0, stream>>>(
        Cp, be1, Hlin_bf, v0e1, v1e1, hv0, hv1);
    // 2. encoder attention
    attn_fused<<<dim3(N), dim3(512), 0, stream>>>(Hlin_bf, hv0, hv1, col_idx, row_cnt, Hgat_bf);
    // 3. Z split-K=8 partials
    gemm_mfma<2, 0, 8, 0><<<dim3(H2 / 128, N / 64, 8), dim3(256), 0, stream>>>(
        Hgat_bf, W2_bf, b2, Cp, N, H2, H1, nullptr, nullptr, nullptr, nullptr);
    // 4. fused Z-reduce + per-node
    z_pernode<<<dim3(N / 4), dim3(256), 0, stream>>>(
        Cp, b2, emb_table, slab, Wb, bb, Wa, ba, lib, beta_bf, muf, kco, Xd_bf);
    // 5. merged decoder GEMM(+hv) + BD GEMM
    dec_bd<<<dim3((H1 / 128) * (N / 64) + (G / 128) * (N / 64)), dim3(256), 0, stream>>>(
        Xd_bf, Wd1_bf, bd1, Hlin_bf, v0d1, v1d1, hv0, hv1, beta_bf, basisT_bf, BDb);
    // 6. merged decoder attention + NB loss
    post_dec<<<dim3(N + N / 8), dim3(512), 0, stream>>>(
        Hlin_bf, hv0, hv1, col_idx, row_cnt, Hgat_bf,
        BDb, count_m, slab, muf, kco, th_a, eg_a, gm_a, ax_a, ll_row);
    // 7. fused reconstruction GEMM + sq-norm
    gemm_recon_sq<<<dim3(G / 128, N / 64), dim3(256), 0, stream>>>(
        Hgat_bf, Wd2_bf, bd2, nf_bf, sq_part);
    // 8. single-block final reduce
    final_reduce<<<dim3(1), dim3(256), 0, stream>>>(ll_row, sq_part, out);
}

// Round 17
// 186.831 us; speedup vs baseline: 1.0761x; 1.0761x over previous
//
#include <hip/hip_runtime.h>
#include <hip/hip_bf16.h>
#include <math.h>

#define N 4096
#define G 2048
#define H1 512
#define H2 128
#define HEADS 8
#define EMB 16
#define C 20
#define S 4
#define CH 64
#define CIN_D (H2 + EMB)   // 144
#define KD_PAD 160         // CIN_D padded to multiple of 32
#define KB_PAD 32          // C padded to 32
#define CAP 128
#define EPSV 1e-6f

typedef __attribute__((ext_vector_type(8))) short short8;
typedef __attribute__((ext_vector_type(8))) short bf16x8;
typedef __attribute__((ext_vector_type(4))) float f32x4;

__device__ __forceinline__ unsigned short f2b(float x) {
    __hip_bfloat16 h = __float2bfloat16(x);
    return *reinterpret_cast<unsigned short*>(&h);
}
__device__ __forceinline__ float b2f(unsigned short u) {
    unsigned int x = ((unsigned int)u) << 16;
    return __uint_as_float(x);
}
// Stirling lgamma: ~1e-7 rel for x>=8 (shift loop for smaller x; untaken here
// since th = exp(5) ~ 148).
__device__ __forceinline__ float lgamma_fast(float x) {
    float sh = 0.f;
    while (x < 8.f) { sh -= __logf(x); x += 1.f; }
    float ix = 1.f / x;
    float lx = __logf(x);
    return (x - 0.5f) * lx - x + 0.91893853f
         + ix * (0.08333333f - 0.00277778f * ix * ix) + sh;
}

// ---------------- merged CSR build (bitmask) + prep ----------------
#define SEG_SG   (S * G)
#define SEG_NF4  (N * G / 4)
#define SEG_WE4  (H1 * G / 4)
#define SEG_W24  (H2 * H1 / 4)
#define SEG_WD1E (H1 * KD_PAD)
#define SEG_WD24 (G * H1 / 4)
#define SEG_BTE  (G * KB_PAD)
#define PREP_TOTAL (SEG_SG + SEG_NF4 + SEG_WE4 + SEG_W24 + SEG_WD1E + SEG_WD24 + SEG_BTE)
#define CSR_BLOCKS (N / 4)
#define PREP_BLOCKS ((PREP_TOTAL + 255) / 256)

__device__ __forceinline__ void cvt4(const float* __restrict__ in,
                                     unsigned short* __restrict__ out, int i) {
    float4 v = ((const float4*)in)[i];
    ushort4 o;
    o.x = f2b(v.x); o.y = f2b(v.y); o.z = f2b(v.z); o.w = f2b(v.w);
    ((ushort4*)out)[i] = o;
}

__global__ __launch_bounds__(256) void csr_prep(const float* __restrict__ adj,
                                                int* __restrict__ col_idx,
                                                int* __restrict__ row_cnt,
                                                const float* __restrict__ logtheta,
                                                const float* __restrict__ gamma,
                                                float* __restrict__ th_a, float* __restrict__ eg_a,
                                                float* __restrict__ gm_a, float* __restrict__ ax_a,
                                                const float* __restrict__ node_f,
                                                unsigned short* __restrict__ nf_bf,
                                                const float* __restrict__ We1,
                                                unsigned short* __restrict__ We1_bf,
                                                const float* __restrict__ W2,
                                                unsigned short* __restrict__ W2_bf,
                                                const float* __restrict__ Wd1,
                                                unsigned short* __restrict__ Wd1_bf,
                                                const float* __restrict__ Wd2,
                                                unsigned short* __restrict__ Wd2_bf,
                                                const float* __restrict__ basis,
                                                unsigned short* __restrict__ basisT_bf) {
    int b = blockIdx.x;
    if (b < CSR_BLOCKS) {
        // bitmask CSR: lane owns 64 contiguous columns -> no serial ballot chain
        int wv = threadIdx.x >> 6, lane = threadIdx.x & 63;
        int i = b * 4 + wv;
        const float4* row4 = (const float4*)(adj + (size_t)i * N);
        unsigned long long mask = 0ull;
        #pragma unroll
        for (int q = 0; q < 16; ++q) {
            float4 v = row4[lane * 16 + q];
            if (v.x != 0.f) mask |= 1ull << (q * 4 + 0);
            if (v.y != 0.f) mask |= 1ull << (q * 4 + 1);
            if (v.z != 0.f) mask |= 1ull << (q * 4 + 2);
            if (v.w != 0.f) mask |= 1ull << (q * 4 + 3);
        }
        int cnt = __popcll(mask);
        int incl = cnt;
        #pragma unroll
        for (int off = 1; off < 64; off <<= 1) {
            int v = __shfl_up(incl, off);
            if (lane >= off) incl += v;
        }
        int ofs = incl - cnt;                 // exclusive prefix
        int total = __shfl(incl, 63);
        int* cols = col_idx + (size_t)i * CAP;
        unsigned long long mm = mask;
        while (mm) {
            int j = __ffsll(mm) - 1;
            if (ofs < CAP) cols[ofs] = lane * 64 + j;
            ++ofs;
            mm &= mm - 1;
        }
        if (lane == 0) row_cnt[i] = total < CAP ? total : CAP;
        return;
    }
    int idx = (b - CSR_BLOCKS) * 256 + threadIdx.x;
    if (idx < SEG_SG) {
        float th = __expf(logtheta[idx]);
        float gm = gamma[idx];
        th_a[idx] = th;
        eg_a[idx] = __expf(gm);
        gm_a[idx] = gm;
        ax_a[idx] = th * __logf(th + EPSV) - lgammaf(th + EPSV);
        return;
    }
    idx -= SEG_SG;
    if (idx < SEG_NF4) { cvt4(node_f, nf_bf, idx); return; }
    idx -= SEG_NF4;
    if (idx < SEG_WE4) { cvt4(We1, We1_bf, idx); return; }
    idx -= SEG_WE4;
    if (idx < SEG_W24) { cvt4(W2, W2_bf, idx); return; }
    idx -= SEG_W24;
    if (idx < SEG_WD1E) {
        int n = idx / KD_PAD, k = idx - n * KD_PAD;
        Wd1_bf[idx] = f2b(k < CIN_D ? Wd1[n * CIN_D + k] : 0.f);
        return;
    }
    idx -= SEG_WD1E;
    if (idx < SEG_WD24) { cvt4(Wd2, Wd2_bf, idx); return; }
    idx -= SEG_WD24;
    if (idx < SEG_BTE) {
        int g = idx >> 5, c = idx & 31;
        basisT_bf[idx] = f2b(c < C ? basis[c * G + g] : 0.f);
    }
}

// ---------------- bf16 MFMA GEMM, optional split-K, optional hv epilogue ----------------
#define LDP 40
template<int FM, int OBF, int KS, int HV>
__global__ __launch_bounds__(256) void gemm_mfma(const unsigned short* __restrict__ A,
                                                 const unsigned short* __restrict__ B,
                                                 const float* __restrict__ bias,
                                                 void* __restrict__ Cout,
                                                 int M, int Nc, int K,
                                                 const float* __restrict__ v0f,
                                                 const float* __restrict__ v1f,
                                                 float* __restrict__ hv0,
                                                 float* __restrict__ hv1) {
    constexpr int BMT = FM * 32;
    __shared__ short As[BMT * LDP];
    __shared__ short Bs[128 * LDP];
    int bn = blockIdx.x, bm = blockIdx.y;
    int kz = (KS > 1) ? blockIdx.z : 0;
    int t = threadIdx.x;
    int lane = t & 63, wid = t >> 6;
    int wr = wid >> 1, wc = wid & 1;
    f32x4 acc[FM][4] = {};
    const short* Ag = (const short*)A + (size_t)(bm * BMT) * K;
    const short* Bg = (const short*)B + (size_t)(bn * 128) * K;
    int r0 = t >> 2, q0 = t & 3;
    int rbase = (lane & 15);
    int koff = (lane >> 4) * 8;
    int kbeg = kz * (K / KS), kend = kbeg + K / KS;

    for (int k0 = kbeg; k0 < kend; k0 += 32) {
        short8 a0 = *(const short8*)(Ag + (size_t)r0 * K + k0 + q0 * 8);
        short8 a1;
        if constexpr (FM == 4) a1 = *(const short8*)(Ag + (size_t)(r0 + 64) * K + k0 + q0 * 8);
        short8 b0 = *(const short8*)(Bg + (size_t)r0 * K + k0 + q0 * 8);
        short8 b1 = *(const short8*)(Bg + (size_t)(r0 + 64) * K + k0 + q0 * 8);
        __syncthreads();
        *(short8*)(As + r0 * LDP + q0 * 8) = a0;
        if constexpr (FM == 4) *(short8*)(As + (r0 + 64) * LDP + q0 * 8) = a1;
        *(short8*)(Bs + r0 * LDP + q0 * 8) = b0;
        *(short8*)(Bs + (r0 + 64) * LDP + q0 * 8) = b1;
        __syncthreads();
        bf16x8 af[FM], bfr[4];
        #pragma unroll
        for (int m = 0; m < FM; ++m)
            af[m] = *(const bf16x8*)(As + (wr * FM * 16 + m * 16 + rbase) * LDP + koff);
        #pragma unroll
        for (int n = 0; n < 4; ++n)
            bfr[n] = *(const bf16x8*)(Bs + (wc * 64 + n * 16 + rbase) * LDP + koff);
        #pragma unroll
        for (int m = 0; m < FM; ++m)
            #pragma unroll
            for (int n = 0; n < 4; ++n)
                acc[m][n] = __builtin_amdgcn_mfma_f32_16x16x32_bf16(af[m], bfr[n], acc[m][n], 0, 0, 0);
    }
    int colb = bn * 128 + wc * 64;
    int rowb = bm * BMT + wr * FM * 16;
    #pragma unroll
    for (int m = 0; m < FM; ++m) {
        #pragma unroll
        for (int n = 0; n < 4; ++n) {
            int col = colb + n * 16 + (lane & 15);
            int row0 = rowb + m * 16 + (lane >> 4) * 4;
            if constexpr (KS > 1) {
                float* Cp = (float*)Cout + (size_t)kz * M * Nc;
                #pragma unroll
                for (int r = 0; r < 4; ++r)
                    Cp[(size_t)(row0 + r) * Nc + col] = acc[m][n][r];
            } else {
                float bs = bias ? bias[col] : 0.f;
                #pragma unroll
                for (int r = 0; r < 4; ++r) {
                    float v = acc[m][n][r] + bs;
                    if constexpr (OBF)
                        ((unsigned short*)Cout)[(size_t)(row0 + r) * Nc + col] = f2b(v);
                    else
                        ((float*)Cout)[(size_t)(row0 + r) * Nc + col] = v;
                }
            }
        }
    }
    if constexpr (HV) {
        int h = colb >> 6;
        #pragma unroll
        for (int m = 0; m < FM; ++m) {
            #pragma unroll
            for (int r = 0; r < 4; ++r) {
                int row = rowb + m * 16 + (lane >> 4) * 4 + r;
                float p0 = 0.f, p1 = 0.f;
                #pragma unroll
                for (int n = 0; n < 4; ++n) {
                    int col = colb + n * 16 + (lane & 15);
                    float v = acc[m][n][r] + bias[col];
                    p0 += v * v0f[col];
                    p1 += v * v1f[col];
                }
                p0 += __shfl_xor(p0, 1); p0 += __shfl_xor(p0, 2);
                p0 += __shfl_xor(p0, 4); p0 += __shfl_xor(p0, 8);
                p1 += __shfl_xor(p1, 1); p1 += __shfl_xor(p1, 2);
                p1 += __shfl_xor(p1, 4); p1 += __shfl_xor(p1, 8);
                if ((lane & 15) == 0) {
                    hv0[row * HEADS + h] = p0;
                    hv1[row * HEADS + h] = p1;
                }
            }
        }
    }
}

// ---------------- shared FM=2, bf16-out GEMM body for the merged dec_bd kernel ----------------
template<int HV>
__device__ __forceinline__ void gemm_body2(const unsigned short* __restrict__ A,
                                           const unsigned short* __restrict__ B,
                                           const float* __restrict__ bias,
                                           unsigned short* __restrict__ Cout,
                                           int K, int Nc, int bn, int bm,
                                           const float* __restrict__ v0f,
                                           const float* __restrict__ v1f,
                                           float* __restrict__ hv0,
                                           float* __restrict__ hv1,
                                           short* As, short* Bs) {
    int t = threadIdx.x;
    int lane = t & 63, wid = t >> 6;
    int wr = wid >> 1, wc = wid & 1;
    f32x4 acc[2][4] = {};
    const short* Ag = (const short*)A + (size_t)(bm * 64) * K;
    const short* Bg = (const short*)B + (size_t)(bn * 128) * K;
    int r0 = t >> 2, q0 = t & 3;
    int rbase = (lane & 15);
    int koff = (lane >> 4) * 8;
    for (int k0 = 0; k0 < K; k0 += 32) {
        short8 a0 = *(const short8*)(Ag + (size_t)r0 * K + k0 + q0 * 8);
        short8 b0 = *(const short8*)(Bg + (size_t)r0 * K + k0 + q0 * 8);
        short8 b1 = *(const short8*)(Bg + (size_t)(r0 + 64) * K + k0 + q0 * 8);
        __syncthreads();
        *(short8*)(As + r0 * LDP + q0 * 8) = a0;
        *(short8*)(Bs + r0 * LDP + q0 * 8) = b0;
        *(short8*)(Bs + (r0 + 64) * LDP + q0 * 8) = b1;
        __syncthreads();
        bf16x8 af[2], bfr[4];
        #pragma unroll
        for (int m = 0; m < 2; ++m)
            af[m] = *(const bf16x8*)(As + (wr * 32 + m * 16 + rbase) * LDP + koff);
        #pragma unroll
        for (int n = 0; n < 4; ++n)
            bfr[n] = *(const bf16x8*)(Bs + (wc * 64 + n * 16 + rbase) * LDP + koff);
        #pragma unroll
        for (int m = 0; m < 2; ++m)
            #pragma unroll
            for (int n = 0; n < 4; ++n)
                acc[m][n] = __builtin_amdgcn_mfma_f32_16x16x32_bf16(af[m], bfr[n], acc[m][n], 0, 0, 0);
    }
    int colb = bn * 128 + wc * 64;
    int rowb = bm * 64 + wr * 32;
    #pragma unroll
    for (int m = 0; m < 2; ++m) {
        #pragma unroll
        for (int n = 0; n < 4; ++n) {
            int col = colb + n * 16 + (lane & 15);
            int row0 = rowb + m * 16 + (lane >> 4) * 4;
            float bs = bias ? bias[col] : 0.f;
            #pragma unroll
            for (int r = 0; r < 4; ++r)
                Cout[(size_t)(row0 + r) * Nc + col] = f2b(acc[m][n][r] + bs);
        }
    }
    if constexpr (HV) {
        int h = colb >> 6;
        #pragma unroll
        for (int m = 0; m < 2; ++m) {
            #pragma unroll
            for (int r = 0; r < 4; ++r) {
                int row = rowb + m * 16 + (lane >> 4) * 4 + r;
                float p0 = 0.f, p1 = 0.f;
                #pragma unroll
                for (int n = 0; n < 4; ++n) {
                    int col = colb + n * 16 + (lane & 15);
                    float v = acc[m][n][r] + bias[col];
                    p0 += v * v0f[col];
                    p1 += v * v1f[col];
                }
                p0 += __shfl_xor(p0, 1); p0 += __shfl_xor(p0, 2);
                p0 += __shfl_xor(p0, 4); p0 += __shfl_xor(p0, 8);
                p1 += __shfl_xor(p1, 1); p1 += __shfl_xor(p1, 2);
                p1 += __shfl_xor(p1, 4); p1 += __shfl_xor(p1, 8);
                if ((lane & 15) == 0) {
                    hv0[row * HEADS + h] = p0;
                    hv1[row * HEADS + h] = p1;
                }
            }
        }
    }
}

// merged: blocks [0,256) decoder GEMM (K=160, +hv); blocks [256,1280) BD GEMM (K=32)
__global__ __launch_bounds__(256) void dec_bd(const unsigned short* __restrict__ Xd_bf,
                                              const unsigned short* __restrict__ Wd1_bf,
                                              const float* __restrict__ bd1,
                                              unsigned short* __restrict__ Hlin_bf,
                                              const float* __restrict__ v0d1,
                                              const float* __restrict__ v1d1,
                                              float* __restrict__ hv0,
                                              float* __restrict__ hv1,
                                              const unsigned short* __restrict__ beta_bf,
                                              const unsigned short* __restrict__ basisT_bf,
                                              unsigned short* __restrict__ BDb) {
    __shared__ short As[64 * LDP];
    __shared__ short Bs[128 * LDP];
    int b = blockIdx.x;
    if (b < (H1 / 128) * (N / 64)) {
        gemm_body2<1>(Xd_bf, Wd1_bf, bd1, Hlin_bf, KD_PAD, H1,
                      b % (H1 / 128), b / (H1 / 128), v0d1, v1d1, hv0, hv1, As, Bs);
    } else {
        int b2 = b - (H1 / 128) * (N / 64);
        gemm_body2<0>(beta_bf, basisT_bf, nullptr, BDb, KB_PAD, G,
                      b2 % (G / 128), b2 / (G / 128), nullptr, nullptr, nullptr, nullptr, As, Bs);
    }
}

// ---------------- split-K reduce + bf16 out + fused head dots (Nc=512) ----------------
template<int KS>
__global__ __launch_bounds__(256) void reduce_k_hv(const float* __restrict__ Cp,
                                                   const float* __restrict__ bias,
                                                   unsigned short* __restrict__ out,
                                                   const float* __restrict__ v0f,
                                                   const float* __restrict__ v1f,
                                                   float* __restrict__ hv0,
                                                   float* __restrict__ hv1) {
    constexpr int total4 = N * H1 / 4;
    int t = threadIdx.x;
    int i = blockIdx.x * 256 + t;
    float4 s = ((const float4*)Cp)[i];
    #pragma unroll
    for (int ks = 1; ks < KS; ++ks) {
        float4 v = ((const float4*)(Cp + (size_t)ks * total4 * 4))[i];
        s.x += v.x; s.y += v.y; s.z += v.z; s.w += v.w;
    }
    int col = (i * 4) & (H1 - 1);
    s.x += bias[col]; s.y += bias[col + 1]; s.z += bias[col + 2]; s.w += bias[col + 3];
    ushort4 o;
    o.x = f2b(s.x); o.y = f2b(s.y); o.z = f2b(s.z); o.w = f2b(s.w);
    ((ushort4*)out)[i] = o;
    int row = (i * 4) >> 9;
    int h = col >> 6;
    float4 w0 = *(const float4*)(v0f + col);
    float4 w1 = *(const float4*)(v1f + col);
    float p0 = s.x * w0.x + s.y * w0.y + s.z * w0.z + s.w * w0.w;
    float p1 = s.x * w1.x + s.y * w1.y + s.z * w1.z + s.w * w1.w;
    p0 += __shfl_xor(p0, 1); p0 += __shfl_xor(p0, 2);
    p0 += __shfl_xor(p0, 4); p0 += __shfl_xor(p0, 8);
    p1 += __shfl_xor(p1, 1); p1 += __shfl_xor(p1, 2);
    p1 += __shfl_xor(p1, 4); p1 += __shfl_xor(p1, 8);
    if ((t & 15) == 0) {
        hv0[row * HEADS + h] = p0;
        hv1[row * HEADS + h] = p1;
    }
}

// ---------------- fused Z split-K reduce + per-node (wave = node) ----------------
__global__ __launch_bounds__(256) void z_pernode(const float* __restrict__ Cp,
                                                 const float* __restrict__ b2,
                                                 const float* __restrict__ emb_table,
                                                 const int* __restrict__ slab,
                                                 const float* __restrict__ Wb,
                                                 const float* __restrict__ bb,
                                                 const float* __restrict__ Wa,
                                                 const float* __restrict__ ba,
                                                 const float* __restrict__ lib,
                                                 unsigned short* __restrict__ beta_bf,
                                                 float* __restrict__ muf,
                                                 float* __restrict__ kco,
                                                 unsigned short* __restrict__ Xdb) {
    __shared__ float sZ[4][H2];
    __shared__ float sE[4][EMB];
    __shared__ float sLog[4][C];
    __shared__ float sAl[4];
    int wv = threadIdx.x >> 6;
    int lane = threadIdx.x & 63;
    int i = blockIdx.x * 4 + wv;
    float z0 = 0.f, z1 = 0.f;
    #pragma unroll
    for (int ks = 0; ks < 8; ++ks) {
        const float* P = Cp + (size_t)ks * N * H2 + (size_t)i * H2;
        z0 += P[lane];
        z1 += P[64 + lane];
    }
    z0 += b2[lane];
    z1 += b2[64 + lane];
    sZ[wv][lane] = z0;
    sZ[wv][64 + lane] = z1;
    int s = slab[i];
    if (lane < EMB) sE[wv][lane] = emb_table[s * EMB + lane];
    __syncthreads();
    Xdb[(size_t)i * KD_PAD + lane] = f2b(z0);
    Xdb[(size_t)i * KD_PAD + 64 + lane] = f2b(z1);
    if (lane < EMB) Xdb[(size_t)i * KD_PAD + H2 + lane] = f2b(sE[wv][lane]);
    if (lane < KD_PAD - CIN_D) Xdb[(size_t)i * KD_PAD + CIN_D + lane] = 0;
    if (lane < C) {
        float acc = bb[lane];
        for (int k = 0; k < H2; ++k) {
            float z = sZ[wv][k];
            float e = z > 0.f ? z : expm1f(z);
            acc += e * Wb[lane * H2 + k];
        }
        sLog[wv][lane] = acc;
    }
    __syncthreads();
    if (lane == 0) {
        float mx = sLog[wv][0];
        for (int c = 1; c < C; ++c) mx = fmaxf(mx, sLog[wv][c]);
        float sm = 0.f;
        for (int c = 0; c < C; ++c) { float e = __expf(sLog[wv][c] - mx); sLog[wv][c] = e; sm += e; }
        for (int c = 0; c < C; ++c) sLog[wv][c] /= sm;
    }
    __syncthreads();
    if (lane < KB_PAD) beta_bf[(size_t)i * KB_PAD + lane] = (lane < C) ? f2b(sLog[wv][lane]) : 0;
    float x0 = z0; x0 = x0 > 0.f ? x0 : expm1f(x0);
    float x1 = z1; x1 = x1 > 0.f ? x1 : expm1f(x1);
    float p = x0 * Wa[lane] + x1 * Wa[64 + lane];
    if (lane < EMB) {
        float x2 = sE[wv][lane]; x2 = x2 > 0.f ? x2 : expm1f(x2);
        p += x2 * Wa[H2 + lane];
    }
    #pragma unroll
    for (int m = 32; m; m >>= 1) p += __shfl_xor(p, m);
    if (lane == 0) sAl[wv] = p + ba[0];
    __syncthreads();
    if (lane == 0) {
        float A = sAl[wv], L = lib[i];
        muf[i] = L * __expf(A);
        kco[i] = __logf(L) + A;
    }
}

// ---------------- fused reconstruction GEMM (64x128 tile) + (nf - Xr)^2 ----------------
__global__ __launch_bounds__(256) void gemm_recon_sq(const unsigned short* __restrict__ A,
                                                     const unsigned short* __restrict__ B,
                                                     const float* __restrict__ bias,
                                                     const unsigned short* __restrict__ nfb,
                                                     float* __restrict__ sq_part) {
    constexpr int K = H1;
    __shared__ short As[64 * LDP];
    __shared__ short Bs[128 * LDP];
    __shared__ float red[4][32];
    int bn = blockIdx.x, bm = blockIdx.y;
    int t = threadIdx.x;
    int lane = t & 63, wid = t >> 6;
    int wr = wid >> 1, wc = wid & 1;
    f32x4 acc[2][4] = {};
    const short* Ag = (const short*)A + (size_t)(bm * 64) * K;
    const short* Bg = (const short*)B + (size_t)(bn * 128) * K;
    int r0 = t >> 2, q0 = t & 3;
    int rbase = (lane & 15);
    int koff = (lane >> 4) * 8;

    for (int k0 = 0; k0 < K; k0 += 32) {
        short8 a0 = *(const short8*)(Ag + (size_t)r0 * K + k0 + q0 * 8);
        short8 b0 = *(const short8*)(Bg + (size_t)r0 * K + k0 + q0 * 8);
        short8 b1 = *(const short8*)(Bg + (size_t)(r0 + 64) * K + k0 + q0 * 8);
        __syncthreads();
        *(short8*)(As + r0 * LDP + q0 * 8) = a0;
        *(short8*)(Bs + r0 * LDP + q0 * 8) = b0;
        *(short8*)(Bs + (r0 + 64) * LDP + q0 * 8) = b1;
        __syncthreads();
        bf16x8 af[2], bfr[4];
        #pragma unroll
        for (int m = 0; m < 2; ++m)
            af[m] = *(const bf16x8*)(As + (wr * 32 + m * 16 + rbase) * LDP + koff);
        #pragma unroll
        for (int n = 0; n < 4; ++n)
            bfr[n] = *(const bf16x8*)(Bs + (wc * 64 + n * 16 + rbase) * LDP + koff);
        #pragma unroll
        for (int m = 0; m < 2; ++m)
            #pragma unroll
            for (int n = 0; n < 4; ++n)
                acc[m][n] = __builtin_amdgcn_mfma_f32_16x16x32_bf16(af[m], bfr[n], acc[m][n], 0, 0, 0);
    }
    int colb = bn * 128 + wc * 64;
    int rowb = bm * 64 + wr * 32;
    float part[2][4];
    #pragma unroll
    for (int m = 0; m < 2; ++m) {
        #pragma unroll
        for (int r = 0; r < 4; ++r) part[m][r] = 0.f;
        #pragma unroll
        for (int n = 0; n < 4; ++n) {
            int col = colb + n * 16 + (lane & 15);
            float bs = bias[col];
            int row0 = rowb + m * 16 + (lane >> 4) * 4;
            #pragma unroll
            for (int r = 0; r < 4; ++r) {
                float d = b2f(nfb[(size_t)(row0 + r) * G + col]) - (acc[m][n][r] + bs);
                part[m][r] += d * d;
            }
        }
    }
    #pragma unroll
    for (int m = 0; m < 2; ++m)
        #pragma unroll
        for (int r = 0; r < 4; ++r) {
            float v = part[m][r];
            v += __shfl_xor(v, 1); v += __shfl_xor(v, 2);
            v += __shfl_xor(v, 4); v += __shfl_xor(v, 8);
            part[m][r] = v;
        }
    if ((lane & 15) == 0) {
        int q = lane >> 4;
        #pragma unroll
        for (int m = 0; m < 2; ++m)
            #pragma unroll
            for (int r = 0; r < 4; ++r)
                red[wid][m * 16 + q * 4 + r] = part[m][r];
    }
    __syncthreads();
    if (t < 64) {
        int wr2 = t >> 5, loc = t & 31;
        float v = red[wr2 * 2 + 0][loc] + red[wr2 * 2 + 1][loc];
        sq_part[(size_t)(bm * 64 + t) * 16 + bn] = v;
    }
}

// ---------------- NB log-likelihood: elementwise, wave-per-row, bf16 BD ----------------
__global__ __launch_bounds__(256) void nb_loss_ew(const unsigned short* __restrict__ BDb,
                                                  const float* __restrict__ cm,
                                                  const int* __restrict__ slab,
                                                  const float* __restrict__ muf,
                                                  const float* __restrict__ kco,
                                                  const float* __restrict__ th_a,
                                                  const float* __restrict__ eg_a,
                                                  const float* __restrict__ gm_a,
                                                  const float* __restrict__ ax_a,
                                                  float* __restrict__ ll_row) {
    int row = blockIdx.x * 4 + (threadIdx.x >> 6);
    int lane = threadIdx.x & 63;
    int sl = slab[row];
    float mufv = muf[row], kcov = kco[row];
    const unsigned short* bdr = BDb + (size_t)row * G;
    const float* cmr = cm + (size_t)row * G;
    size_t sgb = (size_t)sl * G;
    float acc = 0.f;
    #pragma unroll 2
    for (int it = 0; it < G / 256; ++it) {
        int c = it * 256 + lane * 4;
        ushort4 bdu = *(const ushort4*)(bdr + c);
        f32x4 k4  = *(const f32x4*)(cmr + c);
        f32x4 th4 = *(const f32x4*)(th_a + sgb + c);
        f32x4 eg4 = *(const f32x4*)(eg_a + sgb + c);
        f32x4 gm4 = *(const f32x4*)(gm_a + sgb + c);
        f32x4 ax4 = *(const f32x4*)(ax_a + sgb + c);
        float bdv[4] = {b2f(bdu.x), b2f(bdu.y), b2f(bdu.z), b2f(bdu.w)};
        #pragma unroll
        for (int j = 0; j < 4; ++j) {
            float th = th4[j], k = k4[j];
            float ebd = bdv[j] + EPSV;
            float lbd = __logf(ebd);
            float mu = mufv * ebd * eg4[j];
            float lgx = lgamma_fast(k + th + EPSV);
            acc += lgx + ax4[j] - (th + k) * __logf(th + mu + EPSV)
                 + k * (kcov + lbd + gm4[j]);
        }
    }
    #pragma unroll
    for (int m = 32; m; m >>= 1) acc += __shfl_xor(acc, m);
    if (lane == 0) ll_row[row] = acc;
}

// ---------------- fused attention: weights in LDS + aggregation + elu -> bf16 ----------------
__global__ __launch_bounds__(512) void attn_fused(const unsigned short* __restrict__ Hb,
                                                  const float* __restrict__ hv0,
                                                  const float* __restrict__ hv1,
                                                  const int* __restrict__ col_idx,
                                                  const int* __restrict__ row_cnt,
                                                  unsigned short* __restrict__ out) {
    __shared__ int scols[CAP];
    __shared__ float sw[CAP][HEADS];
    __shared__ float sden[HEADS];
    __shared__ float red[8][64 * 8];
    int i = blockIdx.x;
    int t = threadIdx.x;
    int cnt = row_cnt[i];
    const int* cols = col_idx + (size_t)i * CAP;
    if (t < cnt) scols[t] = cols[t];
    __syncthreads();
    for (int idx = t; idx < cnt * HEADS; idx += 512) {
        int e = idx >> 3, h = idx & 7;
        int j = scols[e];
        float x = hv0[i * HEADS + h] + hv1[j * HEADS + h];
        sw[e][h] = __expf(1.f / (1.f + __expf(-x)) - 0.5f);
    }
    __syncthreads();
    if (t < HEADS) {
        float d = 0.f;
        for (int e = 0; e < cnt; ++e) d += sw[e][t];
        sden[t] = 1.f / d;
    }
    __syncthreads();
    int slot = t >> 6;
    int cg = t & 63;
    int h = cg >> 3;
    float inv = sden[h];
    float acc[8];
    #pragma unroll
    for (int k = 0; k < 8; ++k) acc[k] = 0.f;
    for (int e = slot; e < cnt; e += 8) {
        int j = scols[e];
        float wv = sw[e][h] * inv;
        short8 hv = ((const short8*)(Hb + (size_t)j * H1))[cg];
        #pragma unroll
        for (int k = 0; k < 8; ++k)
            acc[k] += wv * b2f((unsigned short)hv[k]);
    }
    #pragma unroll
    for (int k = 0; k < 8; ++k) red[slot][cg * 8 + k] = acc[k];
    __syncthreads();
    if (slot < 4) {
        #pragma unroll
        for (int k = 0; k < 8; ++k) red[slot][cg * 8 + k] += red[slot + 4][cg * 8 + k];
    }
    __syncthreads();
    if (slot < 2) {
        #pragma unroll
        for (int k = 0; k < 8; ++k) red[slot][cg * 8 + k] += red[slot + 2][cg * 8 + k];
    }
    __syncthreads();
    if (slot == 0) {
        short8 o;
        #pragma unroll
        for (int k = 0; k < 8; ++k) {
            float v = red[0][cg * 8 + k] + red[1][cg * 8 + k];
            v = (v > 0.f) ? v : expm1f(v);
            o[k] = (short)f2b(v);
        }
        ((short8*)(out + (size_t)i * H1))[cg] = o;
    }
}

// ---------------- single-block final reduce ----------------
__global__ __launch_bounds__(256) void final_reduce(const float* __restrict__ ll_row,
                                                    const float* __restrict__ sq_part,
                                                    float* __restrict__ out) {
    int t = threadIdx.x;
    float s1 = 0.f, sb = 0.f;
    for (int row = t; row < N; row += 256) {
        s1 += ll_row[row];
        float s2 = 0.f;
        #pragma unroll
        for (int j = 0; j < 16; ++j) s2 += sq_part[(size_t)row * 16 + j];
        sb += sqrtf(s2);
    }
    __shared__ float r1[256], r2[256];
    r1[t] = s1; r2[t] = sb;
    __syncthreads();
    for (int o = 128; o; o >>= 1) {
        if (t < o) { r1[t] += r1[t + o]; r2[t] += r2[t + o]; }
        __syncthreads();
    }
    if (t == 0) out[0] = -(r1[0] / (float)N) + 0.1f * (r2[0] / (float)N);
}

extern "C" void kernel_launch(void* const* d_in, const int* in_sizes, int n_in,
                              void* d_out, int out_size, void* d_ws, size_t ws_size,
                              hipStream_t stream) {
    const float* adj       = (const float*)d_in[0];
    const float* node_f    = (const float*)d_in[1];
    const float* count_m   = (const float*)d_in[2];
    const float* lib       = (const float*)d_in[3];
    const int*   slab      = (const int*)d_in[4];
    const float* basis     = (const float*)d_in[5];
    const float* We1       = (const float*)d_in[6];
    const float* be1       = (const float*)d_in[7];
    const float* v0e1      = (const float*)d_in[8];
    const float* v1e1      = (const float*)d_in[9];
    const float* W2        = (const float*)d_in[10];
    const float* b2        = (const float*)d_in[11];
    const float* Wd1       = (const float*)d_in[12];
    const float* bd1       = (const float*)d_in[13];
    const float* v0d1      = (const float*)d_in[14];
    const float* v1d1      = (const float*)d_in[15];
    const float* Wd2       = (const float*)d_in[16];
    const float* bd2       = (const float*)d_in[17];
    const float* Wa        = (const float*)d_in[18];
    const float* ba        = (const float*)d_in[19];
    const float* Wb        = (const float*)d_in[20];
    const float* bb        = (const float*)d_in[21];
    const float* gamma     = (const float*)d_in[22];
    const float* logtheta  = (const float*)d_in[23];
    const float* emb_table = (const float*)d_in[24];
    float* out = (float*)d_out;

    char* w = (char*)d_ws;
    auto alloc = [&](size_t bytes) { void* p = (void*)w; w += (bytes + 255) & ~(size_t)255; return p; };
    int*   col_idx = (int*)  alloc((size_t)N * CAP * 4);
    int*   row_cnt = (int*)  alloc((size_t)N * 4);
    unsigned short* Hlin_bf = (unsigned short*)alloc((size_t)N * H1 * 2);
    unsigned short* Hgat_bf = (unsigned short*)alloc((size_t)N * H1 * 2);
    unsigned short* Xd_bf   = (unsigned short*)alloc((size_t)N * KD_PAD * 2);
    unsigned short* beta_bf = (unsigned short*)alloc((size_t)N * KB_PAD * 2);
    float* muf     = (float*)alloc((size_t)N * 4);
    float* kco     = (float*)alloc((size_t)N * 4);
    float* hv0     = (float*)alloc((size_t)N * HEADS * 4);
    float* hv1     = (float*)alloc((size_t)N * HEADS * 4);
    float* th_a    = (float*)alloc((size_t)S * G * 4);
    float* eg_a    = (float*)alloc((size_t)S * G * 4);
    float* gm_a    = (float*)alloc((size_t)S * G * 4);
    float* ax_a    = (float*)alloc((size_t)S * G * 4);
    float* Cp      = (float*)alloc((size_t)4 * N * H1 * 4);   // 32 MB split-K partials
    unsigned short* BDb = (unsigned short*)alloc((size_t)N * G * 2);
    float* ll_row  = (float*)alloc((size_t)N * 4);
    float* sq_part = (float*)alloc((size_t)N * 16 * 4);
    unsigned short* nf_bf    = (unsigned short*)alloc((size_t)N * G * 2);
    unsigned short* We1_bf   = (unsigned short*)alloc((size_t)H1 * G * 2);
    unsigned short* W2_bf    = (unsigned short*)alloc((size_t)H2 * H1 * 2);
    unsigned short* Wd1_bf   = (unsigned short*)alloc((size_t)H1 * KD_PAD * 2);
    unsigned short* Wd2_bf   = (unsigned short*)alloc((size_t)G * H1 * 2);
    unsigned short* basisT_bf= (unsigned short*)alloc((size_t)G * KB_PAD * 2);

    // 0. merged CSR (bitmask) + prep
    csr_prep<<<dim3(CSR_BLOCKS + PREP_BLOCKS), dim3(256), 0, stream>>>(
        adj, col_idx, row_cnt, logtheta, gamma, th_a, eg_a, gm_a, ax_a,
        node_f, nf_bf, We1, We1_bf, W2, W2_bf, Wd1, Wd1_bf, Wd2, Wd2_bf, basis, basisT_bf);

    // 1. encoder linear, split-K=4 -> reduce(+head dots) -> bf16 Hlin + hv
    gemm_mfma<2, 0, 4, 0><<<dim3(H1 / 128, N / 64, 4), dim3(256), 0, stream>>>(
        nf_bf, We1_bf, be1, Cp, N, H1, G, nullptr, nullptr, nullptr, nullptr);
    reduce_k_hv<4><<<dim3(N * H1 / 4 / 256), dim3(256), 0, stream>>>(
        Cp, be1, Hlin_bf, v0e1, v1e1, hv0, hv1);
    // 2. encoder attention
    attn_fused<<<dim3(N), dim3(512), 0, stream>>>(Hlin_bf, hv0, hv1, col_idx, row_cnt, Hgat_bf);
    // 3. Z split-K=8 partials
    gemm_mfma<2, 0, 8, 0><<<dim3(H2 / 128, N / 64, 8), dim3(256), 0, stream>>>(
        Hgat_bf, W2_bf, b2, Cp, N, H2, H1, nullptr, nullptr, nullptr, nullptr);
    // 4. fused Z-reduce + per-node
    z_pernode<<<dim3(N / 4), dim3(256), 0, stream>>>(
        Cp, b2, emb_table, slab, Wb, bb, Wa, ba, lib, beta_bf, muf, kco, Xd_bf);
    // 5. merged decoder GEMM(+hv) + BD GEMM
    dec_bd<<<dim3((H1 / 128) * (N / 64) + (G / 128) * (N / 64)), dim3(256), 0, stream>>>(
        Xd_bf, Wd1_bf, bd1, Hlin_bf, v0d1, v1d1, hv0, hv1, beta_bf, basisT_bf, BDb);
    // 6. NB log-likelihood elementwise (high occupancy, separate)
    nb_loss_ew<<<dim3(N / 4), dim3(256), 0, stream>>>(
        BDb, count_m, slab, muf, kco, th_a, eg_a, gm_a, ax_a, ll_row);
    // 7. decoder attention
    attn_fused<<<dim3(N), dim3(512), 0, stream>>>(Hlin_bf, hv0, hv1, col_idx, row_cnt, Hgat_bf);
    // 8. fused reconstruction GEMM + sq-norm
    gemm_recon_sq<<<dim3(G / 128, N / 64), dim3(256), 0, stream>>>(
        Hgat_bf, Wd2_bf, bd2, nf_bf, sq_part);
    // 9. single-block final reduce
    final_reduce<<<dim3(1), dim3(256), 0, stream>>>(ll_row, sq_part, out);
}

// Round 18
// 185.006 us; speedup vs baseline: 1.0867x; 1.0099x over previous
//
#include <hip/hip_runtime.h>
#include <hip/hip_bf16.h>
#include <math.h>

#define N 4096
#define G 2048
#define H1 512
#define H2 128
#define HEADS 8
#define EMB 16
#define C 20
#define S 4
#define CH 64
#define CIN_D (H2 + EMB)   // 144
#define KD_PAD 160         // CIN_D padded to multiple of 32
#define KB_PAD 32          // C padded to 32
#define CAP 128
#define EPSV 1e-6f

typedef __attribute__((ext_vector_type(8))) short short8;
typedef __attribute__((ext_vector_type(8))) short bf16x8;
typedef __attribute__((ext_vector_type(4))) float f32x4;

__device__ __forceinline__ unsigned short f2b(float x) {
    __hip_bfloat16 h = __float2bfloat16(x);
    return *reinterpret_cast<unsigned short*>(&h);
}
__device__ __forceinline__ float b2f(unsigned short u) {
    unsigned int x = ((unsigned int)u) << 16;
    return __uint_as_float(x);
}
// Stirling lgamma: ~1e-7 rel for x>=8 (shift loop for smaller x; untaken here
// since th = exp(5) ~ 148).
__device__ __forceinline__ float lgamma_fast(float x) {
    float sh = 0.f;
    while (x < 8.f) { sh -= __logf(x); x += 1.f; }
    float ix = 1.f / x;
    float lx = __logf(x);
    return (x - 0.5f) * lx - x + 0.91893853f
         + ix * (0.08333333f - 0.00277778f * ix * ix) + sh;
}

// ---------------- merged CSR build (block-per-row, ballot) + prep ----------------
#define SEG_SG    (S * G)            // 8192
#define SEG_NF16  (N * G / 16)       // 524288: 4 float4 each
#define SEG_WE16  (H1 * G / 16)      // 65536: 4 float4 each
#define SEG_W24   (H2 * H1 / 4)      // 16384: 1 float4
#define SEG_WD1E  (H1 * KD_PAD)      // 81920: scalar
#define SEG_WD216 (G * H1 / 16)      // 65536: 4 float4 each
#define SEG_BTE   (G * KB_PAD)       // 65536: scalar
#define PREP_TOTAL (SEG_SG + SEG_NF16 + SEG_WE16 + SEG_W24 + SEG_WD1E + SEG_WD216 + SEG_BTE)
#define CSR_BLOCKS N
#define PREP_BLOCKS ((PREP_TOTAL + 255) / 256)

__device__ __forceinline__ void cvt4(const float* __restrict__ in,
                                     unsigned short* __restrict__ out, int i) {
    float4 v = ((const float4*)in)[i];
    ushort4 o;
    o.x = f2b(v.x); o.y = f2b(v.y); o.z = f2b(v.z); o.w = f2b(v.w);
    ((ushort4*)out)[i] = o;
}
__device__ __forceinline__ void cvt16(const float* __restrict__ in,
                                      unsigned short* __restrict__ out, int i) {
    #pragma unroll
    for (int q = 0; q < 4; ++q) cvt4(in, out, i * 4 + q);
}

__global__ __launch_bounds__(256) void csr_prep(const float* __restrict__ adj,
                                                int* __restrict__ col_idx,
                                                int* __restrict__ row_cnt,
                                                const float* __restrict__ logtheta,
                                                const float* __restrict__ gamma,
                                                float* __restrict__ th_a, float* __restrict__ eg_a,
                                                float* __restrict__ gm_a, float* __restrict__ ax_a,
                                                const float* __restrict__ node_f,
                                                unsigned short* __restrict__ nf_bf,
                                                const float* __restrict__ We1,
                                                unsigned short* __restrict__ We1_bf,
                                                const float* __restrict__ W2,
                                                unsigned short* __restrict__ W2_bf,
                                                const float* __restrict__ Wd1,
                                                unsigned short* __restrict__ Wd1_bf,
                                                const float* __restrict__ Wd2,
                                                unsigned short* __restrict__ Wd2_bf,
                                                const float* __restrict__ basis,
                                                unsigned short* __restrict__ basisT_bf) {
    int b = blockIdx.x;
    if (b < CSR_BLOCKS) {
        // block = row; wave wv covers columns [wv*1024, wv*1024+1024)
        __shared__ int wtot[4];
        int wv = threadIdx.x >> 6, lane = threadIdx.x & 63;
        int i = b;
        const float* rowp = adj + (size_t)i * N;
        unsigned long long mymask = 0ull;
        #pragma unroll
        for (int c = 0; c < 16; ++c) {
            float v = rowp[wv * 1024 + c * 64 + lane];     // coalesced 256B/instr
            unsigned long long m = __ballot(v != 0.f);     // independent ballots
            if (lane == c) mymask = m;
        }
        int cnt = (lane < 16) ? __popcll(mymask) : 0;
        int incl = cnt;
        #pragma unroll
        for (int off = 1; off < 64; off <<= 1) {
            int vv = __shfl_up(incl, off);
            if (lane >= off) incl += vv;
        }
        int wtotal = __shfl(incl, 63);
        if (lane == 0) wtot[wv] = wtotal;
        __syncthreads();
        int base = 0;
        #pragma unroll
        for (int wq = 0; wq < 4; ++wq) if (wq < wv) base += wtot[wq];
        int ofs = base + incl - cnt;      // exclusive within row
        int* cols = col_idx + (size_t)i * CAP;
        if (lane < 16) {
            unsigned long long mm = mymask;
            int colbase = wv * 1024 + lane * 64;
            while (mm) {
                int j = __ffsll(mm) - 1;
                if (ofs < CAP) cols[ofs] = colbase + j;
                ++ofs;
                mm &= mm - 1;
            }
        }
        if (threadIdx.x == 0) {
            int total_all = wtot[0] + wtot[1] + wtot[2] + wtot[3];
            row_cnt[i] = total_all < CAP ? total_all : CAP;
        }
        return;
    }
    int idx = (b - CSR_BLOCKS) * 256 + threadIdx.x;
    if (idx < SEG_SG) {
        float th = __expf(logtheta[idx]);
        float gm = gamma[idx];
        th_a[idx] = th;
        eg_a[idx] = __expf(gm);
        gm_a[idx] = gm;
        ax_a[idx] = th * __logf(th + EPSV) - lgammaf(th + EPSV);
        return;
    }
    idx -= SEG_SG;
    if (idx < SEG_NF16) { cvt16(node_f, nf_bf, idx); return; }
    idx -= SEG_NF16;
    if (idx < SEG_WE16) { cvt16(We1, We1_bf, idx); return; }
    idx -= SEG_WE16;
    if (idx < SEG_W24) { cvt4(W2, W2_bf, idx); return; }
    idx -= SEG_W24;
    if (idx < SEG_WD1E) {
        int n = idx / KD_PAD, k = idx - n * KD_PAD;
        Wd1_bf[idx] = f2b(k < CIN_D ? Wd1[n * CIN_D + k] : 0.f);
        return;
    }
    idx -= SEG_WD1E;
    if (idx < SEG_WD216) { cvt16(Wd2, Wd2_bf, idx); return; }
    idx -= SEG_WD216;
    if (idx < SEG_BTE) {
        int g = idx >> 5, c = idx & 31;
        basisT_bf[idx] = f2b(c < C ? basis[c * G + g] : 0.f);
    }
}

// ---------------- bf16 MFMA GEMM, optional split-K, optional hv epilogue ----------------
#define LDP 40
template<int FM, int OBF, int KS, int HV>
__global__ __launch_bounds__(256) void gemm_mfma(const unsigned short* __restrict__ A,
                                                 const unsigned short* __restrict__ B,
                                                 const float* __restrict__ bias,
                                                 void* __restrict__ Cout,
                                                 int M, int Nc, int K,
                                                 const float* __restrict__ v0f,
                                                 const float* __restrict__ v1f,
                                                 float* __restrict__ hv0,
                                                 float* __restrict__ hv1) {
    constexpr int BMT = FM * 32;
    __shared__ short As[BMT * LDP];
    __shared__ short Bs[128 * LDP];
    int bn = blockIdx.x, bm = blockIdx.y;
    int kz = (KS > 1) ? blockIdx.z : 0;
    int t = threadIdx.x;
    int lane = t & 63, wid = t >> 6;
    int wr = wid >> 1, wc = wid & 1;
    f32x4 acc[FM][4] = {};
    const short* Ag = (const short*)A + (size_t)(bm * BMT) * K;
    const short* Bg = (const short*)B + (size_t)(bn * 128) * K;
    int r0 = t >> 2, q0 = t & 3;
    int rbase = (lane & 15);
    int koff = (lane >> 4) * 8;
    int kbeg = kz * (K / KS), kend = kbeg + K / KS;

    for (int k0 = kbeg; k0 < kend; k0 += 32) {
        short8 a0 = *(const short8*)(Ag + (size_t)r0 * K + k0 + q0 * 8);
        short8 a1;
        if constexpr (FM == 4) a1 = *(const short8*)(Ag + (size_t)(r0 + 64) * K + k0 + q0 * 8);
        short8 b0 = *(const short8*)(Bg + (size_t)r0 * K + k0 + q0 * 8);
        short8 b1 = *(const short8*)(Bg + (size_t)(r0 + 64) * K + k0 + q0 * 8);
        __syncthreads();
        *(short8*)(As + r0 * LDP + q0 * 8) = a0;
        if constexpr (FM == 4) *(short8*)(As + (r0 + 64) * LDP + q0 * 8) = a1;
        *(short8*)(Bs + r0 * LDP + q0 * 8) = b0;
        *(short8*)(Bs + (r0 + 64) * LDP + q0 * 8) = b1;
        __syncthreads();
        bf16x8 af[FM], bfr[4];
        #pragma unroll
        for (int m = 0; m < FM; ++m)
            af[m] = *(const bf16x8*)(As + (wr * FM * 16 + m * 16 + rbase) * LDP + koff);
        #pragma unroll
        for (int n = 0; n < 4; ++n)
            bfr[n] = *(const bf16x8*)(Bs + (wc * 64 + n * 16 + rbase) * LDP + koff);
        #pragma unroll
        for (int m = 0; m < FM; ++m)
            #pragma unroll
            for (int n = 0; n < 4; ++n)
                acc[m][n] = __builtin_amdgcn_mfma_f32_16x16x32_bf16(af[m], bfr[n], acc[m][n], 0, 0, 0);
    }
    int colb = bn * 128 + wc * 64;
    int rowb = bm * BMT + wr * FM * 16;
    #pragma unroll
    for (int m = 0; m < FM; ++m) {
        #pragma unroll
        for (int n = 0; n < 4; ++n) {
            int col = colb + n * 16 + (lane & 15);
            int row0 = rowb + m * 16 + (lane >> 4) * 4;
            if constexpr (KS > 1) {
                float* Cp = (float*)Cout + (size_t)kz * M * Nc;
                #pragma unroll
                for (int r = 0; r < 4; ++r)
                    Cp[(size_t)(row0 + r) * Nc + col] = acc[m][n][r];
            } else {
                float bs = bias ? bias[col] : 0.f;
                #pragma unroll
                for (int r = 0; r < 4; ++r) {
                    float v = acc[m][n][r] + bs;
                    if constexpr (OBF)
                        ((unsigned short*)Cout)[(size_t)(row0 + r) * Nc + col] = f2b(v);
                    else
                        ((float*)Cout)[(size_t)(row0 + r) * Nc + col] = v;
                }
            }
        }
    }
    if constexpr (HV) {
        int h = colb >> 6;
        #pragma unroll
        for (int m = 0; m < FM; ++m) {
            #pragma unroll
            for (int r = 0; r < 4; ++r) {
                int row = rowb + m * 16 + (lane >> 4) * 4 + r;
                float p0 = 0.f, p1 = 0.f;
                #pragma unroll
                for (int n = 0; n < 4; ++n) {
                    int col = colb + n * 16 + (lane & 15);
                    float v = acc[m][n][r] + bias[col];
                    p0 += v * v0f[col];
                    p1 += v * v1f[col];
                }
                p0 += __shfl_xor(p0, 1); p0 += __shfl_xor(p0, 2);
                p0 += __shfl_xor(p0, 4); p0 += __shfl_xor(p0, 8);
                p1 += __shfl_xor(p1, 1); p1 += __shfl_xor(p1, 2);
                p1 += __shfl_xor(p1, 4); p1 += __shfl_xor(p1, 8);
                if ((lane & 15) == 0) {
                    hv0[row * HEADS + h] = p0;
                    hv1[row * HEADS + h] = p1;
                }
            }
        }
    }
}

// ---------------- shared FM=2, bf16-out GEMM body for the merged dec_bd kernel ----------------
template<int HV>
__device__ __forceinline__ void gemm_body2(const unsigned short* __restrict__ A,
                                           const unsigned short* __restrict__ B,
                                           const float* __restrict__ bias,
                                           unsigned short* __restrict__ Cout,
                                           int K, int Nc, int bn, int bm,
                                           const float* __restrict__ v0f,
                                           const float* __restrict__ v1f,
                                           float* __restrict__ hv0,
                                           float* __restrict__ hv1,
                                           short* As, short* Bs) {
    int t = threadIdx.x;
    int lane = t & 63, wid = t >> 6;
    int wr = wid >> 1, wc = wid & 1;
    f32x4 acc[2][4] = {};
    const short* Ag = (const short*)A + (size_t)(bm * 64) * K;
    const short* Bg = (const short*)B + (size_t)(bn * 128) * K;
    int r0 = t >> 2, q0 = t & 3;
    int rbase = (lane & 15);
    int koff = (lane >> 4) * 8;
    for (int k0 = 0; k0 < K; k0 += 32) {
        short8 a0 = *(const short8*)(Ag + (size_t)r0 * K + k0 + q0 * 8);
        short8 b0 = *(const short8*)(Bg + (size_t)r0 * K + k0 + q0 * 8);
        short8 b1 = *(const short8*)(Bg + (size_t)(r0 + 64) * K + k0 + q0 * 8);
        __syncthreads();
        *(short8*)(As + r0 * LDP + q0 * 8) = a0;
        *(short8*)(Bs + r0 * LDP + q0 * 8) = b0;
        *(short8*)(Bs + (r0 + 64) * LDP + q0 * 8) = b1;
        __syncthreads();
        bf16x8 af[2], bfr[4];
        #pragma unroll
        for (int m = 0; m < 2; ++m)
            af[m] = *(const bf16x8*)(As + (wr * 32 + m * 16 + rbase) * LDP + koff);
        #pragma unroll
        for (int n = 0; n < 4; ++n)
            bfr[n] = *(const bf16x8*)(Bs + (wc * 64 + n * 16 + rbase) * LDP + koff);
        #pragma unroll
        for (int m = 0; m < 2; ++m)
            #pragma unroll
            for (int n = 0; n < 4; ++n)
                acc[m][n] = __builtin_amdgcn_mfma_f32_16x16x32_bf16(af[m], bfr[n], acc[m][n], 0, 0, 0);
    }
    int colb = bn * 128 + wc * 64;
    int rowb = bm * 64 + wr * 32;
    #pragma unroll
    for (int m = 0; m < 2; ++m) {
        #pragma unroll
        for (int n = 0; n < 4; ++n) {
            int col = colb + n * 16 + (lane & 15);
            int row0 = rowb + m * 16 + (lane >> 4) * 4;
            float bs = bias ? bias[col] : 0.f;
            #pragma unroll
            for (int r = 0; r < 4; ++r)
                Cout[(size_t)(row0 + r) * Nc + col] = f2b(acc[m][n][r] + bs);
        }
    }
    if constexpr (HV) {
        int h = colb >> 6;
        #pragma unroll
        for (int m = 0; m < 2; ++m) {
            #pragma unroll
            for (int r = 0; r < 4; ++r) {
                int row = rowb + m * 16 + (lane >> 4) * 4 + r;
                float p0 = 0.f, p1 = 0.f;
                #pragma unroll
                for (int n = 0; n < 4; ++n) {
                    int col = colb + n * 16 + (lane & 15);
                    float v = acc[m][n][r] + bias[col];
                    p0 += v * v0f[col];
                    p1 += v * v1f[col];
                }
                p0 += __shfl_xor(p0, 1); p0 += __shfl_xor(p0, 2);
                p0 += __shfl_xor(p0, 4); p0 += __shfl_xor(p0, 8);
                p1 += __shfl_xor(p1, 1); p1 += __shfl_xor(p1, 2);
                p1 += __shfl_xor(p1, 4); p1 += __shfl_xor(p1, 8);
                if ((lane & 15) == 0) {
                    hv0[row * HEADS + h] = p0;
                    hv1[row * HEADS + h] = p1;
                }
            }
        }
    }
}

// merged: blocks [0,256) decoder GEMM (K=160, +hv); blocks [256,1280) BD GEMM (K=32)
__global__ __launch_bounds__(256) void dec_bd(const unsigned short* __restrict__ Xd_bf,
                                              const unsigned short* __restrict__ Wd1_bf,
                                              const float* __restrict__ bd1,
                                              unsigned short* __restrict__ Hlin_bf,
                                              const float* __restrict__ v0d1,
                                              const float* __restrict__ v1d1,
                                              float* __restrict__ hv0,
                                              float* __restrict__ hv1,
                                              const unsigned short* __restrict__ beta_bf,
                                              const unsigned short* __restrict__ basisT_bf,
                                              unsigned short* __restrict__ BDb) {
    __shared__ short As[64 * LDP];
    __shared__ short Bs[128 * LDP];
    int b = blockIdx.x;
    if (b < (H1 / 128) * (N / 64)) {
        gemm_body2<1>(Xd_bf, Wd1_bf, bd1, Hlin_bf, KD_PAD, H1,
                      b % (H1 / 128), b / (H1 / 128), v0d1, v1d1, hv0, hv1, As, Bs);
    } else {
        int b2 = b - (H1 / 128) * (N / 64);
        gemm_body2<0>(beta_bf, basisT_bf, nullptr, BDb, KB_PAD, G,
                      b2 % (G / 128), b2 / (G / 128), nullptr, nullptr, nullptr, nullptr, As, Bs);
    }
}

// ---------------- split-K reduce + bf16 out + fused head dots (Nc=512) ----------------
template<int KS>
__global__ __launch_bounds__(256) void reduce_k_hv(const float* __restrict__ Cp,
                                                   const float* __restrict__ bias,
                                                   unsigned short* __restrict__ out,
                                                   const float* __restrict__ v0f,
                                                   const float* __restrict__ v1f,
                                                   float* __restrict__ hv0,
                                                   float* __restrict__ hv1) {
    constexpr int total4 = N * H1 / 4;
    int t = threadIdx.x;
    int i = blockIdx.x * 256 + t;
    float4 s = ((const float4*)Cp)[i];
    #pragma unroll
    for (int ks = 1; ks < KS; ++ks) {
        float4 v = ((const float4*)(Cp + (size_t)ks * total4 * 4))[i];
        s.x += v.x; s.y += v.y; s.z += v.z; s.w += v.w;
    }
    int col = (i * 4) & (H1 - 1);
    s.x += bias[col]; s.y += bias[col + 1]; s.z += bias[col + 2]; s.w += bias[col + 3];
    ushort4 o;
    o.x = f2b(s.x); o.y = f2b(s.y); o.z = f2b(s.z); o.w = f2b(s.w);
    ((ushort4*)out)[i] = o;
    int row = (i * 4) >> 9;
    int h = col >> 6;
    float4 w0 = *(const float4*)(v0f + col);
    float4 w1 = *(const float4*)(v1f + col);
    float p0 = s.x * w0.x + s.y * w0.y + s.z * w0.z + s.w * w0.w;
    float p1 = s.x * w1.x + s.y * w1.y + s.z * w1.z + s.w * w1.w;
    p0 += __shfl_xor(p0, 1); p0 += __shfl_xor(p0, 2);
    p0 += __shfl_xor(p0, 4); p0 += __shfl_xor(p0, 8);
    p1 += __shfl_xor(p1, 1); p1 += __shfl_xor(p1, 2);
    p1 += __shfl_xor(p1, 4); p1 += __shfl_xor(p1, 8);
    if ((t & 15) == 0) {
        hv0[row * HEADS + h] = p0;
        hv1[row * HEADS + h] = p1;
    }
}

// ---------------- fused Z split-K reduce + per-node (wave = node) ----------------
__global__ __launch_bounds__(256) void z_pernode(const float* __restrict__ Cp,
                                                 const float* __restrict__ b2,
                                                 const float* __restrict__ emb_table,
                                                 const int* __restrict__ slab,
                                                 const float* __restrict__ Wb,
                                                 const float* __restrict__ bb,
                                                 const float* __restrict__ Wa,
                                                 const float* __restrict__ ba,
                                                 const float* __restrict__ lib,
                                                 unsigned short* __restrict__ beta_bf,
                                                 float* __restrict__ muf,
                                                 float* __restrict__ kco,
                                                 unsigned short* __restrict__ Xdb) {
    __shared__ float sZ[4][H2];
    __shared__ float sE[4][EMB];
    __shared__ float sLog[4][C];
    __shared__ float sAl[4];
    int wv = threadIdx.x >> 6;
    int lane = threadIdx.x & 63;
    int i = blockIdx.x * 4 + wv;
    float z0 = 0.f, z1 = 0.f;
    #pragma unroll
    for (int ks = 0; ks < 8; ++ks) {
        const float* P = Cp + (size_t)ks * N * H2 + (size_t)i * H2;
        z0 += P[lane];
        z1 += P[64 + lane];
    }
    z0 += b2[lane];
    z1 += b2[64 + lane];
    sZ[wv][lane] = z0;
    sZ[wv][64 + lane] = z1;
    int s = slab[i];
    if (lane < EMB) sE[wv][lane] = emb_table[s * EMB + lane];
    __syncthreads();
    Xdb[(size_t)i * KD_PAD + lane] = f2b(z0);
    Xdb[(size_t)i * KD_PAD + 64 + lane] = f2b(z1);
    if (lane < EMB) Xdb[(size_t)i * KD_PAD + H2 + lane] = f2b(sE[wv][lane]);
    if (lane < KD_PAD - CIN_D) Xdb[(size_t)i * KD_PAD + CIN_D + lane] = 0;
    if (lane < C) {
        float acc = bb[lane];
        for (int k = 0; k < H2; ++k) {
            float z = sZ[wv][k];
            float e = z > 0.f ? z : expm1f(z);
            acc += e * Wb[lane * H2 + k];
        }
        sLog[wv][lane] = acc;
    }
    __syncthreads();
    if (lane == 0) {
        float mx = sLog[wv][0];
        for (int c = 1; c < C; ++c) mx = fmaxf(mx, sLog[wv][c]);
        float sm = 0.f;
        for (int c = 0; c < C; ++c) { float e = __expf(sLog[wv][c] - mx); sLog[wv][c] = e; sm += e; }
        for (int c = 0; c < C; ++c) sLog[wv][c] /= sm;
    }
    __syncthreads();
    if (lane < KB_PAD) beta_bf[(size_t)i * KB_PAD + lane] = (lane < C) ? f2b(sLog[wv][lane]) : 0;
    float x0 = z0; x0 = x0 > 0.f ? x0 : expm1f(x0);
    float x1 = z1; x1 = x1 > 0.f ? x1 : expm1f(x1);
    float p = x0 * Wa[lane] + x1 * Wa[64 + lane];
    if (lane < EMB) {
        float x2 = sE[wv][lane]; x2 = x2 > 0.f ? x2 : expm1f(x2);
        p += x2 * Wa[H2 + lane];
    }
    #pragma unroll
    for (int m = 32; m; m >>= 1) p += __shfl_xor(p, m);
    if (lane == 0) sAl[wv] = p + ba[0];
    __syncthreads();
    if (lane == 0) {
        float A = sAl[wv], L = lib[i];
        muf[i] = L * __expf(A);
        kco[i] = __logf(L) + A;
    }
}

// ---------------- fused reconstruction GEMM (64x128 tile) + (nf - Xr)^2 ----------------
__global__ __launch_bounds__(256) void gemm_recon_sq(const unsigned short* __restrict__ A,
                                                     const unsigned short* __restrict__ B,
                                                     const float* __restrict__ bias,
                                                     const unsigned short* __restrict__ nfb,
                                                     float* __restrict__ sq_part) {
    constexpr int K = H1;
    __shared__ short As[64 * LDP];
    __shared__ short Bs[128 * LDP];
    __shared__ float red[4][32];
    int bn = blockIdx.x, bm = blockIdx.y;
    int t = threadIdx.x;
    int lane = t & 63, wid = t >> 6;
    int wr = wid >> 1, wc = wid & 1;
    f32x4 acc[2][4] = {};
    const short* Ag = (const short*)A + (size_t)(bm * 64) * K;
    const short* Bg = (const short*)B + (size_t)(bn * 128) * K;
    int r0 = t >> 2, q0 = t & 3;
    int rbase = (lane & 15);
    int koff = (lane >> 4) * 8;

    for (int k0 = 0; k0 < K; k0 += 32) {
        short8 a0 = *(const short8*)(Ag + (size_t)r0 * K + k0 + q0 * 8);
        short8 b0 = *(const short8*)(Bg + (size_t)r0 * K + k0 + q0 * 8);
        short8 b1 = *(const short8*)(Bg + (size_t)(r0 + 64) * K + k0 + q0 * 8);
        __syncthreads();
        *(short8*)(As + r0 * LDP + q0 * 8) = a0;
        *(short8*)(Bs + r0 * LDP + q0 * 8) = b0;
        *(short8*)(Bs + (r0 + 64) * LDP + q0 * 8) = b1;
        __syncthreads();
        bf16x8 af[2], bfr[4];
        #pragma unroll
        for (int m = 0; m < 2; ++m)
            af[m] = *(const bf16x8*)(As + (wr * 32 + m * 16 + rbase) * LDP + koff);
        #pragma unroll
        for (int n = 0; n < 4; ++n)
            bfr[n] = *(const bf16x8*)(Bs + (wc * 64 + n * 16 + rbase) * LDP + koff);
        #pragma unroll
        for (int m = 0; m < 2; ++m)
            #pragma unroll
            for (int n = 0; n < 4; ++n)
                acc[m][n] = __builtin_amdgcn_mfma_f32_16x16x32_bf16(af[m], bfr[n], acc[m][n], 0, 0, 0);
    }
    int colb = bn * 128 + wc * 64;
    int rowb = bm * 64 + wr * 32;
    float part[2][4];
    #pragma unroll
    for (int m = 0; m < 2; ++m) {
        #pragma unroll
        for (int r = 0; r < 4; ++r) part[m][r] = 0.f;
        #pragma unroll
        for (int n = 0; n < 4; ++n) {
            int col = colb + n * 16 + (lane & 15);
            float bs = bias[col];
            int row0 = rowb + m * 16 + (lane >> 4) * 4;
            #pragma unroll
            for (int r = 0; r < 4; ++r) {
                float d = b2f(nfb[(size_t)(row0 + r) * G + col]) - (acc[m][n][r] + bs);
                part[m][r] += d * d;
            }
        }
    }
    #pragma unroll
    for (int m = 0; m < 2; ++m)
        #pragma unroll
        for (int r = 0; r < 4; ++r) {
            float v = part[m][r];
            v += __shfl_xor(v, 1); v += __shfl_xor(v, 2);
            v += __shfl_xor(v, 4); v += __shfl_xor(v, 8);
            part[m][r] = v;
        }
    if ((lane & 15) == 0) {
        int q = lane >> 4;
        #pragma unroll
        for (int m = 0; m < 2; ++m)
            #pragma unroll
            for (int r = 0; r < 4; ++r)
                red[wid][m * 16 + q * 4 + r] = part[m][r];
    }
    __syncthreads();
    if (t < 64) {
        int wr2 = t >> 5, loc = t & 31;
        float v = red[wr2 * 2 + 0][loc] + red[wr2 * 2 + 1][loc];
        sq_part[(size_t)(bm * 64 + t) * 16 + bn] = v;
    }
}

// ---------------- NB log-likelihood: elementwise, wave-per-row, bf16 BD ----------------
__global__ __launch_bounds__(256) void nb_loss_ew(const unsigned short* __restrict__ BDb,
                                                  const float* __restrict__ cm,
                                                  const int* __restrict__ slab,
                                                  const float* __restrict__ muf,
                                                  const float* __restrict__ kco,
                                                  const float* __restrict__ th_a,
                                                  const float* __restrict__ eg_a,
                                                  const float* __restrict__ gm_a,
                                                  const float* __restrict__ ax_a,
                                                  float* __restrict__ ll_row) {
    int row = blockIdx.x * 4 + (threadIdx.x >> 6);
    int lane = threadIdx.x & 63;
    int sl = slab[row];
    float mufv = muf[row], kcov = kco[row];
    const unsigned short* bdr = BDb + (size_t)row * G;
    const float* cmr = cm + (size_t)row * G;
    size_t sgb = (size_t)sl * G;
    float acc = 0.f;
    #pragma unroll 2
    for (int it = 0; it < G / 256; ++it) {
        int c = it * 256 + lane * 4;
        ushort4 bdu = *(const ushort4*)(bdr + c);
        f32x4 k4  = *(const f32x4*)(cmr + c);
        f32x4 th4 = *(const f32x4*)(th_a + sgb + c);
        f32x4 eg4 = *(const f32x4*)(eg_a + sgb + c);
        f32x4 gm4 = *(const f32x4*)(gm_a + sgb + c);
        f32x4 ax4 = *(const f32x4*)(ax_a + sgb + c);
        float bdv[4] = {b2f(bdu.x), b2f(bdu.y), b2f(bdu.z), b2f(bdu.w)};
        #pragma unroll
        for (int j = 0; j < 4; ++j) {
            float th = th4[j], k = k4[j];
            float ebd = bdv[j] + EPSV;
            float lbd = __logf(ebd);
            float mu = mufv * ebd * eg4[j];
            float lgx = lgamma_fast(k + th + EPSV);
            acc += lgx + ax4[j] - (th + k) * __logf(th + mu + EPSV)
                 + k * (kcov + lbd + gm4[j]);
        }
    }
    #pragma unroll
    for (int m = 32; m; m >>= 1) acc += __shfl_xor(acc, m);
    if (lane == 0) ll_row[row] = acc;
}

// ---------------- fused attention: weights in LDS + aggregation + elu -> bf16 ----------------
__global__ __launch_bounds__(512) void attn_fused(const unsigned short* __restrict__ Hb,
                                                  const float* __restrict__ hv0,
                                                  const float* __restrict__ hv1,
                                                  const int* __restrict__ col_idx,
                                                  const int* __restrict__ row_cnt,
                                                  unsigned short* __restrict__ out) {
    __shared__ int scols[CAP];
    __shared__ float sw[CAP][HEADS];
    __shared__ float sden[HEADS];
    __shared__ float red[8][64 * 8];
    int i = blockIdx.x;
    int t = threadIdx.x;
    int cnt = row_cnt[i];
    const int* cols = col_idx + (size_t)i * CAP;
    if (t < cnt) scols[t] = cols[t];
    __syncthreads();
    for (int idx = t; idx < cnt * HEADS; idx += 512) {
        int e = idx >> 3, h = idx & 7;
        int j = scols[e];
        float x = hv0[i * HEADS + h] + hv1[j * HEADS + h];
        sw[e][h] = __expf(1.f / (1.f + __expf(-x)) - 0.5f);
    }
    __syncthreads();
    if (t < HEADS) {
        float d = 0.f;
        for (int e = 0; e < cnt; ++e) d += sw[e][t];
        sden[t] = 1.f / d;
    }
    __syncthreads();
    int slot = t >> 6;
    int cg = t & 63;
    int h = cg >> 3;
    float inv = sden[h];
    float acc[8];
    #pragma unroll
    for (int k = 0; k < 8; ++k) acc[k] = 0.f;
    for (int e = slot; e < cnt; e += 8) {
        int j = scols[e];
        float wv = sw[e][h] * inv;
        short8 hv = ((const short8*)(Hb + (size_t)j * H1))[cg];
        #pragma unroll
        for (int k = 0; k < 8; ++k)
            acc[k] += wv * b2f((unsigned short)hv[k]);
    }
    #pragma unroll
    for (int k = 0; k < 8; ++k) red[slot][cg * 8 + k] = acc[k];
    __syncthreads();
    if (slot < 4) {
        #pragma unroll
        for (int k = 0; k < 8; ++k) red[slot][cg * 8 + k] += red[slot + 4][cg * 8 + k];
    }
    __syncthreads();
    if (slot < 2) {
        #pragma unroll
        for (int k = 0; k < 8; ++k) red[slot][cg * 8 + k] += red[slot + 2][cg * 8 + k];
    }
    __syncthreads();
    if (slot == 0) {
        short8 o;
        #pragma unroll
        for (int k = 0; k < 8; ++k) {
            float v = red[0][cg * 8 + k] + red[1][cg * 8 + k];
            v = (v > 0.f) ? v : expm1f(v);
            o[k] = (short)f2b(v);
        }
        ((short8*)(out + (size_t)i * H1))[cg] = o;
    }
}

// ---------------- single-block final reduce ----------------
__global__ __launch_bounds__(256) void final_reduce(const float* __restrict__ ll_row,
                                                    const float* __restrict__ sq_part,
                                                    float* __restrict__ out) {
    int t = threadIdx.x;
    float s1 = 0.f, sb = 0.f;
    for (int row = t; row < N; row += 256) {
        s1 += ll_row[row];
        float s2 = 0.f;
        #pragma unroll
        for (int j = 0; j < 16; ++j) s2 += sq_part[(size_t)row * 16 + j];
        sb += sqrtf(s2);
    }
    __shared__ float r1[256], r2[256];
    r1[t] = s1; r2[t] = sb;
    __syncthreads();
    for (int o = 128; o; o >>= 1) {
        if (t < o) { r1[t] += r1[t + o]; r2[t] += r2[t + o]; }
        __syncthreads();
    }
    if (t == 0) out[0] = -(r1[0] / (float)N) + 0.1f * (r2[0] / (float)N);
}

extern "C" void kernel_launch(void* const* d_in, const int* in_sizes, int n_in,
                              void* d_out, int out_size, void* d_ws, size_t ws_size,
                              hipStream_t stream) {
    const float* adj       = (const float*)d_in[0];
    const float* node_f    = (const float*)d_in[1];
    const float* count_m   = (const float*)d_in[2];
    const float* lib       = (const float*)d_in[3];
    const int*   slab      = (const int*)d_in[4];
    const float* basis     = (const float*)d_in[5];
    const float* We1       = (const float*)d_in[6];
    const float* be1       = (const float*)d_in[7];
    const float* v0e1      = (const float*)d_in[8];
    const float* v1e1      = (const float*)d_in[9];
    const float* W2        = (const float*)d_in[10];
    const float* b2        = (const float*)d_in[11];
    const float* Wd1       = (const float*)d_in[12];
    const float* bd1       = (const float*)d_in[13];
    const float* v0d1      = (const float*)d_in[14];
    const float* v1d1      = (const float*)d_in[15];
    const float* Wd2       = (const float*)d_in[16];
    const float* bd2       = (const float*)d_in[17];
    const float* Wa        = (const float*)d_in[18];
    const float* ba        = (const float*)d_in[19];
    const float* Wb        = (const float*)d_in[20];
    const float* bb        = (const float*)d_in[21];
    const float* gamma     = (const float*)d_in[22];
    const float* logtheta  = (const float*)d_in[23];
    const float* emb_table = (const float*)d_in[24];
    float* out = (float*)d_out;

    char* w = (char*)d_ws;
    auto alloc = [&](size_t bytes) { void* p = (void*)w; w += (bytes + 255) & ~(size_t)255; return p; };
    int*   col_idx = (int*)  alloc((size_t)N * CAP * 4);
    int*   row_cnt = (int*)  alloc((size_t)N * 4);
    unsigned short* Hlin_bf = (unsigned short*)alloc((size_t)N * H1 * 2);
    unsigned short* Hgat_bf = (unsigned short*)alloc((size_t)N * H1 * 2);
    unsigned short* Xd_bf   = (unsigned short*)alloc((size_t)N * KD_PAD * 2);
    unsigned short* beta_bf = (unsigned short*)alloc((size_t)N * KB_PAD * 2);
    float* muf     = (float*)alloc((size_t)N * 4);
    float* kco     = (float*)alloc((size_t)N * 4);
    float* hv0     = (float*)alloc((size_t)N * HEADS * 4);
    float* hv1     = (float*)alloc((size_t)N * HEADS * 4);
    float* th_a    = (float*)alloc((size_t)S * G * 4);
    float* eg_a    = (float*)alloc((size_t)S * G * 4);
    float* gm_a    = (float*)alloc((size_t)S * G * 4);
    float* ax_a    = (float*)alloc((size_t)S * G * 4);
    float* Cp      = (float*)alloc((size_t)4 * N * H1 * 4);   // 32 MB split-K partials
    unsigned short* BDb = (unsigned short*)alloc((size_t)N * G * 2);
    float* ll_row  = (float*)alloc((size_t)N * 4);
    float* sq_part = (float*)alloc((size_t)N * 16 * 4);
    unsigned short* nf_bf    = (unsigned short*)alloc((size_t)N * G * 2);
    unsigned short* We1_bf   = (unsigned short*)alloc((size_t)H1 * G * 2);
    unsigned short* W2_bf    = (unsigned short*)alloc((size_t)H2 * H1 * 2);
    unsigned short* Wd1_bf   = (unsigned short*)alloc((size_t)H1 * KD_PAD * 2);
    unsigned short* Wd2_bf   = (unsigned short*)alloc((size_t)G * H1 * 2);
    unsigned short* basisT_bf= (unsigned short*)alloc((size_t)G * KB_PAD * 2);

    // 0. merged CSR (block-per-row ballot) + prep (4x vectorized)
    csr_prep<<<dim3(CSR_BLOCKS + PREP_BLOCKS), dim3(256), 0, stream>>>(
        adj, col_idx, row_cnt, logtheta, gamma, th_a, eg_a, gm_a, ax_a,
        node_f, nf_bf, We1, We1_bf, W2, W2_bf, Wd1, Wd1_bf, Wd2, Wd2_bf, basis, basisT_bf);

    // 1. encoder linear, split-K=4 -> reduce(+head dots) -> bf16 Hlin + hv
    gemm_mfma<2, 0, 4, 0><<<dim3(H1 / 128, N / 64, 4), dim3(256), 0, stream>>>(
        nf_bf, We1_bf, be1, Cp, N, H1, G, nullptr, nullptr, nullptr, nullptr);
    reduce_k_hv<4><<<dim3(N * H1 / 4 / 256), dim3(256), 0, stream>>>(
        Cp, be1, Hlin_bf, v0e1, v1e1, hv0, hv1);
    // 2. encoder attention
    attn_fused<<<dim3(N), dim3(512), 0, stream>>>(Hlin_bf, hv0, hv1, col_idx, row_cnt, Hgat_bf);
    // 3. Z split-K=8 partials
    gemm_mfma<2, 0, 8, 0><<<dim3(H2 / 128, N / 64, 8), dim3(256), 0, stream>>>(
        Hgat_bf, W2_bf, b2, Cp, N, H2, H1, nullptr, nullptr, nullptr, nullptr);
    // 4. fused Z-reduce + per-node
    z_pernode<<<dim3(N / 4), dim3(256), 0, stream>>>(
        Cp, b2, emb_table, slab, Wb, bb, Wa, ba, lib, beta_bf, muf, kco, Xd_bf);
    // 5. merged decoder GEMM(+hv) + BD GEMM
    dec_bd<<<dim3((H1 / 128) * (N / 64) + (G / 128) * (N / 64)), dim3(256), 0, stream>>>(
        Xd_bf, Wd1_bf, bd1, Hlin_bf, v0d1, v1d1, hv0, hv1, beta_bf, basisT_bf, BDb);
    // 6. NB log-likelihood elementwise
    nb_loss_ew<<<dim3(N / 4), dim3(256), 0, stream>>>(
        BDb, count_m, slab, muf, kco, th_a, eg_a, gm_a, ax_a, ll_row);
    // 7. decoder attention
    attn_fused<<<dim3(N), dim3(512), 0, stream>>>(Hlin_bf, hv0, hv1, col_idx, row_cnt, Hgat_bf);
    // 8. fused reconstruction GEMM + sq-norm
    gemm_recon_sq<<<dim3(G / 128, N / 64), dim3(256), 0, stream>>>(
        Hgat_bf, Wd2_bf, bd2, nf_bf, sq_part);
    // 9. single-block final reduce
    final_reduce<<<dim3(1), dim3(256), 0, stream>>>(ll_row, sq_part, out);
}